// Round 11
// baseline (1039.521 us; speedup 1.0000x reference)
//
#include <hip/hip_runtime.h>

typedef unsigned short u16;
typedef unsigned long long u64;
typedef unsigned u32x4_t __attribute__((ext_vector_type(4)));
typedef _Float16 f16x8_t __attribute__((ext_vector_type(8)));
typedef short    i16x8_t __attribute__((ext_vector_type(8)));
typedef float    f32x4_t __attribute__((ext_vector_type(4)));

// force a loaded value to stay materialized in VGPRs (no remat/sinking)
#define PIN(x) asm volatile("" : "+v"(x))

// ---- helpers ---------------------------------------------------------------
static __device__ __forceinline__ u16 f2h(float f) {
  _Float16 h = (_Float16)f;  // RNE
  return __builtin_bit_cast(u16, h);
}
static __device__ __forceinline__ f32x4_t mfma16h(i16x8_t a, i16x8_t b, f32x4_t c) {
  return __builtin_amdgcn_mfma_f32_16x16x32_f16(
      __builtin_bit_cast(f16x8_t, a), __builtin_bit_cast(f16x8_t, b), c, 0, 0, 0);
}
static __device__ __forceinline__ float sigmoidf_(float x) { return 1.f / (1.f + __expf(-x)); }
static __device__ __forceinline__ float tanhf_(float x) { return 1.f - 2.f / (__expf(2.f * x) + 1.f); }

// true iff none of the four u16 lanes equals the sentinel 0x7FFF
static __device__ __forceinline__ bool no_sent(u64 v) {
  u64 x = v ^ 0x7FFF7FFF7FFF7FFFull;  // sentinel lane -> 0x0000
  return (((x - 0x0001000100010001ull) & ~x & 0x8000800080008000ull) == 0);
}
static __device__ __forceinline__ bool ok16(u32x4_t v) {
  u64 a = ((u64)v[1] << 32) | v[0];
  u64 b = ((u64)v[3] << 32) | v[2];
  return no_sent(a) && no_sent(b);
}

// issue a 16B LLC-coherent load WITHOUT waiting (overlap under compute);
// caller must execute the tied s_waitcnt below before using the value.
static __device__ __forceinline__ u32x4_t llc_issue16(const u32x4_t* p) {
  u32x4_t r;
  asm volatile("global_load_dwordx4 %0, %1, off sc0 sc1" : "=v"(r) : "v"(p));
  return r;
}
// blocking 16B LLC-coherent load (retry path)
static __device__ __forceinline__ u32x4_t llc_load16(const u32x4_t* p) {
  u32x4_t r;
  asm volatile("global_load_dwordx4 %0, %1, off sc0 sc1\n\t"
               "s_waitcnt vmcnt(0)"
               : "=&v"(r) : "v"(p) : "memory");
  return r;
}
// 4B LLC write-through store (bypasses L1/L2, lands at the coherence point)
static __device__ __forceinline__ void llc_store4(unsigned* p, unsigned v) {
  asm volatile("global_store_dword %0, %1, off sc0 sc1" :: "v"(p), "v"(v) : "memory");
}

// ---- prep: LSTM weights pre-swizzled into MFMA fragment order --------------
// wpack[dir][tau][kb][lane][8]: tau = jb*4+g (jb = j-block, g = gate),
// kb in [0,12), lane = quad*16+mrow. Element e: n = g*256+jb*16+mrow,
// k = kb*32+quad*8+e; value = k<128 ? Wi[k][n] : Wh[k-128][n].
__global__ __launch_bounds__(256) void prep_wpack(const float* __restrict__ Wi_f,
                                                  const float* __restrict__ Wh_f,
                                                  const float* __restrict__ Wi_r,
                                                  const float* __restrict__ Wh_r,
                                                  u16* __restrict__ wpack) {
  int id = blockIdx.x * 256 + threadIdx.x;
  if (id >= 786432) return;  // 2*64*12*64*8
  int e = id & 7, r = id >> 3;
  int lane = r & 63; r >>= 6;
  int kb = r % 12; r /= 12;
  int tau = r & 63, dir = r >> 6;
  int mrow = lane & 15, quad = lane >> 4;
  int jb = tau >> 2, g = tau & 3;
  int n = g * 256 + jb * 16 + mrow;
  int k = kb * 32 + quad * 8 + e;
  const float* Wi = dir ? Wi_r : Wi_f;
  const float* Wh = dir ? Wh_r : Wh_f;
  float v = (k < 128) ? Wi[k * 1024 + n] : Wh[(k - 128) * 1024 + n];
  wpack[id] = f2h(v);
}

// ---- prep: poison x1 with the f16-NaN sentinel (re-run every launch) -------
__global__ __launch_bounds__(256) void poison_x1(uint4* __restrict__ x1v) {
  size_t id = (size_t)blockIdx.x * 256 + threadIdx.x;  // 2,097,152 threads
  const uint4 s = {0x7FFF7FFFu, 0x7FFF7FFFu, 0x7FFF7FFFu, 0x7FFF7FFFu};
  x1v[id * 2] = s;
  x1v[id * 2 + 1] = s;  // 32 B/thread -> 64 MB total
}

// ---- prep: MLP W^T in f16 (W1[512][256], W2[256][256], W3[256][128]) -------
__global__ __launch_bounds__(256) void prep_small(const float* __restrict__ W1,
                                                  const float* __restrict__ W2,
                                                  const float* __restrict__ W3,
                                                  u16* __restrict__ w1t,
                                                  u16* __restrict__ w2t,
                                                  u16* __restrict__ w3t) {
  int id = blockIdx.x * 256 + threadIdx.x;
  if (id < 131072) { int n = id >> 9, k = id & 511; w1t[id] = f2h(W1[k * 256 + n]); return; }
  id -= 131072;
  if (id < 65536) { int n = id >> 8, k = id & 255; w2t[id] = f2h(W2[k * 256 + n]); return; }
  id -= 65536;
  if (id < 32768) { int n = id >> 8, k = id & 255; w3t[id] = f2h(W3[k * 128 + n]); }
}

// ---- bidirectional LSTM v14: 2-group interleave, 8-way gate-slice split ----
// v13 postmortem: exchange cost is ONE irreducible LLC round-trip (~4-6K cy)
// inside the serial recurrence; it cannot be shrunk (v12/v13 null), only
// HIDDEN under independent work. v14 gives each block TWO independent
// recurrences (batch groups A=rows[32p,32p+16), B=rows[32p+16,32p+32)) and
// pipelines them: issue both h-probes -> x-proj A+B (hides load latency) ->
// stage/MFMA/gate/store A -> stage/MFMA/gate/store B. A's store has ~0.7 step
// of slack before its next-step consume (was ~0.1) -> transit off the
// critical path. 256 blocks = q(8 slices of 8 taus = 32 h-cols) x dir(2) x
// p(16 pairs). Wh slice 64 KB LDS-resident, Wi 16 VGPR/wave (1 tau/wave).
// Exchange protocol (sentinel 0x7FFF + sc0|sc1) is v13-verbatim. Per-tau
// accumulation order unchanged (bias -> Wi kb0..3 -> Wh kb4..11): numerics
// match v13 (t=0 h-MFMAs run on zeroed ah: exact +0 adds).
__global__ __launch_bounds__(512, 2) void lstm_kernel(
    const float* __restrict__ x0, const u16* __restrict__ wpack,
    const float* __restrict__ bi_f, const float* __restrict__ bh_f,
    const float* __restrict__ bi_r, const float* __restrict__ bh_r,
    u16* __restrict__ x1) {
  __shared__ __align__(16) u16 lwh[8][8][64][8];    // 64 KB Wh kb4..11, 8 taus
  __shared__ __align__(16) u16 ah[2][16][256];      // 16 KB h panels (A,B), swz
  __shared__ __align__(16) float gbuf[2][16][132];  // gate pre-acts (A,B)

  const int tid = threadIdx.x;
  const int lane = tid & 63;
  const int w = tid >> 6;             // wave 0..7 (owns local tau = w)
  const int bid = blockIdx.x;
  const int q = bid >> 5;             // gate-slice 0..7 (32 h-cols each)
  const int rem = bid & 31;
  const int dir = rem >> 4;
  const int p = rem & 15;             // batch pair
  const int b0A = p * 32, b0B = p * 32 + 16;
  const u16* wpk = wpack + (size_t)dir * (64 * 12 * 64 * 8);
  const float* bi = dir ? bi_r : bi_f;
  const float* bh = dir ? bh_r : bh_f;
  const int mrow = lane & 15, quad = lane >> 4;
  const int tauG = 8 * q + w;         // this wave's global tau

  float bias_;
  {
    int n = (tauG & 3) * 256 + (tauG >> 2) * 16 + mrow;
    bias_ = bi[n] + bh[n];
  }

  // Wh kb4..11 for the block's 8 taus -> LDS (4096 frags of 16 B)
#pragma unroll
  for (int r = 0; r < 8; ++r) {
    int d = r * 512 + tid;
    int ltau = d >> 9, lkb = (d >> 6) & 7, ll = d & 63;
    *(i16x8_t*)&lwh[ltau][lkb][ll][0] =
        *(const i16x8_t*)(wpk + (((size_t)(8 * q + ltau) * 12 + 4 + lkb) * 64 + ll) * 8);
  }
  // Wi kb0..3 for the wave's tau -> registers (16 VGPR), pinned
  i16x8_t wir[4];
#pragma unroll
  for (int kb = 0; kb < 4; ++kb) {
    wir[kb] = *(const i16x8_t*)(wpk + (((size_t)tauG * 12 + kb) * 64 + lane) * 8);
    PIN(wir[kb]);
  }
  // h_{-1} = 0 for both groups
  for (int i = tid; i < 2 * 16 * 256; i += 512) ((u16*)ah)[i] = 0;
  __syncthreads();  // lwh + ah ready

  // gate ownership: tid<256 -> group A cells, tid>=256 -> group B cells
  const int gl = tid & 255;
  const int crow = gl >> 4;            // 0..15
  const int cj0 = (gl & 15) * 2;       // 0..30 (2 cells)
  const int grpSel = tid >> 8;         // 0 = A, 1 = B
  const int b0g = grpSel ? b0B : b0A;
  float c0 = 0.f, c1 = 0.f;

  // x-frag bases (per group)
  const float* xbaseA = x0 + (size_t)(b0A + mrow) * 16384 + quad * 8;
  const float* xbaseB = x0 + (size_t)(b0B + mrow) * 16384 + quad * 8;
  // h staging: 16B/thread, each thread waits on exactly one producer's cols
  const int fm = tid >> 5, fj = (tid & 31) * 8;
  const u16* hsrcA = x1 + (size_t)(b0A + fm) * 65536 + dir * 256 + fj;
  const u16* hsrcB = x1 + (size_t)(b0B + fm) * 65536 + dir * 256 + fj;
  u16* ahA_dst = &ah[0][fm][fj ^ ((fm & 7) << 3)];
  u16* ahB_dst = &ah[1][fm][fj ^ ((fm & 7) << 3)];

  for (int t = 0; t < 128; ++t) {
    const int teff = dir ? 127 - t : t;

    // issue both groups' h_{t-1} probes FIRST (latency hides under x-proj)
    u32x4_t hA = {0, 0, 0, 0}, hB = {0, 0, 0, 0};
    if (t > 0) {
      hA = llc_issue16((const u32x4_t*)(hsrcA + (size_t)(t - 1) * 512));
      hB = llc_issue16((const u32x4_t*)(hsrcB + (size_t)(t - 1) * 512));
    }

    // x fragments + x-projection, group A then B (independent of h)
    f32x4_t accA, accB;
    {
      const float* xp = xbaseA + (size_t)teff * 128;
      i16x8_t afx[4];
#pragma unroll
      for (int kb = 0; kb < 4; ++kb) {
        float4 va = *(const float4*)(xp + kb * 32);
        float4 vb = *(const float4*)(xp + kb * 32 + 4);
        i16x8_t v;
        v[0] = (short)f2h(va.x); v[1] = (short)f2h(va.y);
        v[2] = (short)f2h(va.z); v[3] = (short)f2h(va.w);
        v[4] = (short)f2h(vb.x); v[5] = (short)f2h(vb.y);
        v[6] = (short)f2h(vb.z); v[7] = (short)f2h(vb.w);
        afx[kb] = v;
      }
      f32x4_t a = {bias_, bias_, bias_, bias_};
      a = mfma16h(afx[0], wir[0], a);
      a = mfma16h(afx[1], wir[1], a);
      a = mfma16h(afx[2], wir[2], a);
      a = mfma16h(afx[3], wir[3], a);
      accA = a;
    }
    {
      const float* xp = xbaseB + (size_t)teff * 128;
      i16x8_t afx[4];
#pragma unroll
      for (int kb = 0; kb < 4; ++kb) {
        float4 va = *(const float4*)(xp + kb * 32);
        float4 vb = *(const float4*)(xp + kb * 32 + 4);
        i16x8_t v;
        v[0] = (short)f2h(va.x); v[1] = (short)f2h(va.y);
        v[2] = (short)f2h(va.z); v[3] = (short)f2h(va.w);
        v[4] = (short)f2h(vb.x); v[5] = (short)f2h(vb.y);
        v[6] = (short)f2h(vb.z); v[7] = (short)f2h(vb.w);
        afx[kb] = v;
      }
      f32x4_t a = {bias_, bias_, bias_, bias_};
      a = mfma16h(afx[0], wir[0], a);
      a = mfma16h(afx[1], wir[1], a);
      a = mfma16h(afx[2], wir[2], a);
      a = mfma16h(afx[3], wir[3], a);
      accB = a;
    }

    // ---- group A: stage, MFMA, gate, store -------------------------------
    if (t > 0) {
      // materialize the prefetched probes (data-tied waitcnt, no hoisting)
      asm volatile("s_waitcnt vmcnt(0)" : "+v"(hA), "+v"(hB) :: "memory");
      unsigned iter = 0;
      while (!ok16(hA)) {
        __builtin_amdgcn_s_sleep(1);
        hA = llc_load16((const u32x4_t*)(hsrcA + (size_t)(t - 1) * 512));
        if (++iter > (1u << 20)) break;  // fail-safe: bug -> wrong, not hang
      }
      *(u32x4_t*)ahA_dst = hA;
    }
    __syncthreads();  // (B1) ahA ready
    {
      i16x8_t afh[8];
#pragma unroll
      for (int kb = 0; kb < 8; ++kb)
        afh[kb] = *(const i16x8_t*)&ah[0][mrow][(kb * 32 + quad * 8) ^ ((mrow & 7) << 3)];
      f32x4_t a = accA;
#pragma unroll
      for (int kb = 0; kb < 8; ++kb)
        a = mfma16h(afh[kb], *(const i16x8_t*)&lwh[w][kb][lane][0], a);
#pragma unroll
      for (int r = 0; r < 4; ++r) gbuf[0][quad * 4 + r][w * 16 + mrow] = a[r];
    }
    __syncthreads();  // (B2) gbufA ready
    if (grpSel == 0) {
      float hv[2];
#pragma unroll
      for (int e = 0; e < 2; ++e) {
        int jj = cj0 + e;
        int base = (jj >> 4) * 64 + (jj & 15);
        float fg = gbuf[0][crow][base];
        float ig = gbuf[0][crow][base + 16];
        float ag = gbuf[0][crow][base + 32];
        float og = gbuf[0][crow][base + 48];
        float cc = e ? c1 : c0;
        float cv = sigmoidf_(fg) * cc + sigmoidf_(ig) * tanhf_(ag);
        if (e) c1 = cv; else c0 = cv;
        hv[e] = sigmoidf_(og) * tanhf_(cv);
      }
      unsigned pack = (unsigned)f2h(hv[0]) | ((unsigned)f2h(hv[1]) << 16);
      llc_store4((unsigned*)(x1 + ((size_t)((b0g + crow) * 128 + t)) * 512 +
                             dir * 256 + 32 * q + cj0),
                 pack);
    }
    // ---- group B: stage, MFMA, gate, store -------------------------------
    if (t > 0) {  // hB already materialized by the waitcnt above
      unsigned iter = 0;
      while (!ok16(hB)) {
        __builtin_amdgcn_s_sleep(1);
        hB = llc_load16((const u32x4_t*)(hsrcB + (size_t)(t - 1) * 512));
        if (++iter > (1u << 20)) break;
      }
      *(u32x4_t*)ahB_dst = hB;
    }
    __syncthreads();  // (B3) ahB ready; gbufA reads (gate A) done
    {
      i16x8_t afh[8];
#pragma unroll
      for (int kb = 0; kb < 8; ++kb)
        afh[kb] = *(const i16x8_t*)&ah[1][mrow][(kb * 32 + quad * 8) ^ ((mrow & 7) << 3)];
      f32x4_t a = accB;
#pragma unroll
      for (int kb = 0; kb < 8; ++kb)
        a = mfma16h(afh[kb], *(const i16x8_t*)&lwh[w][kb][lane][0], a);
#pragma unroll
      for (int r = 0; r < 4; ++r) gbuf[1][quad * 4 + r][w * 16 + mrow] = a[r];
    }
    __syncthreads();  // (B4) gbufB ready
    if (grpSel == 1) {
      float hv[2];
#pragma unroll
      for (int e = 0; e < 2; ++e) {
        int jj = cj0 + e;
        int base = (jj >> 4) * 64 + (jj & 15);
        float fg = gbuf[1][crow][base];
        float ig = gbuf[1][crow][base + 16];
        float ag = gbuf[1][crow][base + 32];
        float og = gbuf[1][crow][base + 48];
        float cc = e ? c1 : c0;
        float cv = sigmoidf_(fg) * cc + sigmoidf_(ig) * tanhf_(ag);
        if (e) c1 = cv; else c0 = cv;
        hv[e] = sigmoidf_(og) * tanhf_(cv);
      }
      unsigned pack = (unsigned)f2h(hv[0]) | ((unsigned)f2h(hv[1]) << 16);
      llc_store4((unsigned*)(x1 + ((size_t)((b0g + crow) * 128 + t)) * 512 +
                             dir * 256 + 32 * q + cj0),
                 pack);
    }
    // no trailing barrier: next-iter phases are ordered by B1 and LDS proofs
  }
}

// ---- fused MLP + heads (unchanged — passing) ------------------------------
__global__ __launch_bounds__(512, 1) void mlp_kernel(
    const u16* __restrict__ x1, const u16* __restrict__ w1t,
    const u16* __restrict__ w2t, const u16* __restrict__ w3t,
    const float* __restrict__ b1, const float* __restrict__ b2,
    const float* __restrict__ b3, float* __restrict__ out) {
  __shared__ __align__(16) u16 X2[128][264];
  __shared__ __align__(16) u16 X3[128][264];
  const int tid = threadIdx.x;
  const int lane = tid & 63, wv = tid >> 6;
  const int mrow = lane & 15, quad = lane >> 4;
  const int r0 = blockIdx.x * 128;
  const f32x4_t zero4 = {0.f, 0.f, 0.f, 0.f};

  // stage 1: X2[128][256] = leaky(x1[128,512] @ W1 + b1)
  {
    f32x4_t acc[16];
#pragma unroll
    for (int n = 0; n < 16; ++n) acc[n] = zero4;
    for (int kb = 0; kb < 16; ++kb) {
      int k = kb * 32 + quad * 8;
      i16x8_t a = *(const i16x8_t*)(x1 + (size_t)(r0 + wv * 16 + mrow) * 512 + k);
#pragma unroll
      for (int n = 0; n < 16; ++n) {
        i16x8_t b = *(const i16x8_t*)(w1t + (n * 16 + mrow) * 512 + k);
        acc[n] = mfma16h(a, b, acc[n]);
      }
    }
#pragma unroll
    for (int n = 0; n < 16; ++n)
#pragma unroll
      for (int r = 0; r < 4; ++r) {
        int m = wv * 16 + quad * 4 + r;
        int col = n * 16 + mrow;
        float v = acc[n][r] + b1[col];
        v = v > 0.f ? v : 0.1f * v;
        X2[m][col] = f2h(v);
      }
  }
  __syncthreads();

  // stage 2: X3[128][256] = leaky(X2 @ W2 + b2), K=256
  {
    f32x4_t acc[16];
#pragma unroll
    for (int n = 0; n < 16; ++n) acc[n] = zero4;
#pragma unroll
    for (int kb = 0; kb < 8; ++kb) {
      int k = kb * 32 + quad * 8;
      i16x8_t a = *(const i16x8_t*)&X2[wv * 16 + mrow][k];
#pragma unroll
      for (int n = 0; n < 16; ++n) {
        i16x8_t b = *(const i16x8_t*)(w2t + (n * 16 + mrow) * 256 + k);
        acc[n] = mfma16h(a, b, acc[n]);
      }
    }
#pragma unroll
    for (int n = 0; n < 16; ++n)
#pragma unroll
      for (int r = 0; r < 4; ++r) {
        int m = wv * 16 + quad * 4 + r;
        int col = n * 16 + mrow;
        float v = acc[n][r] + b2[col];
        v = v > 0.f ? v : 0.1f * v;
        X3[m][col] = f2h(v);
      }
  }
  __syncthreads();

  // stage 3: XF[128][128] = X3 @ W3 + b3 (fp32; overlays dead X2)
  float (*XF)[130] = (float (*)[130]) & X2[0][0];
  {
    f32x4_t acc[8];
#pragma unroll
    for (int n = 0; n < 8; ++n) acc[n] = zero4;
#pragma unroll
    for (int kb = 0; kb < 8; ++kb) {
      int k = kb * 32 + quad * 8;
      i16x8_t a = *(const i16x8_t*)&X3[wv * 16 + mrow][k];
#pragma unroll
      for (int n = 0; n < 8; ++n) {
        i16x8_t b = *(const i16x8_t*)(w3t + (n * 16 + mrow) * 256 + k);
        acc[n] = mfma16h(a, b, acc[n]);
      }
    }
#pragma unroll
    for (int n = 0; n < 8; ++n)
#pragma unroll
      for (int r = 0; r < 4; ++r) {
        int m = wv * 16 + quad * 4 + r;
        int col = n * 16 + mrow;
        XF[m][col] = acc[n][r] + b3[col];
      }
  }
  __syncthreads();

  // heads: cols 0:64 sigmoid; softmax over [64,72), [72,88), [88,128)
  if (tid < 128) {
    int row = tid;
    float* xr = XF[row];
    float* op = out + (size_t)(r0 + row) * 128;
    for (int cc = 0; cc < 64; ++cc) op[cc] = sigmoidf_(xr[cc]);
  } else if (tid < 256) {
    int row = tid - 128;
    float* xr = XF[row];
    float* op = out + (size_t)(r0 + row) * 128;
    const int s0s[3] = {64, 72, 88};
    const int s1s[3] = {72, 88, 128};
    for (int s = 0; s < 3; ++s) {
      int s0 = s0s[s], s1 = s1s[s];
      float mx = xr[s0];
      for (int q = s0 + 1; q < s1; ++q) mx = fmaxf(mx, xr[q]);
      float sum = 0.f;
      for (int q = s0; q < s1; ++q) { float e = __expf(xr[q] - mx); xr[q] = e; sum += e; }
      float inv = 1.f / sum;
      for (int q = s0; q < s1; ++q) op[q] = xr[q] * inv;
    }
  }
}

// ---- launch ----------------------------------------------------------------
extern "C" void kernel_launch(void* const* d_in, const int* in_sizes, int n_in,
                              void* d_out, int out_size, void* d_ws, size_t ws_size,
                              hipStream_t stream) {
  const float* x0   = (const float*)d_in[0];
  const float* Wi_f = (const float*)d_in[1];
  const float* bi_f = (const float*)d_in[2];
  const float* Wh_f = (const float*)d_in[3];
  const float* bh_f = (const float*)d_in[4];
  const float* Wi_r = (const float*)d_in[5];
  const float* bi_r = (const float*)d_in[6];
  const float* Wh_r = (const float*)d_in[7];
  const float* bh_r = (const float*)d_in[8];
  const float* W1 = (const float*)d_in[9];
  const float* b1 = (const float*)d_in[10];
  const float* W2 = (const float*)d_in[11];
  const float* b2 = (const float*)d_in[12];
  const float* W3 = (const float*)d_in[13];
  const float* b3 = (const float*)d_in[14];
  float* out = (float*)d_out;

  char* ws = (char*)d_ws;
  u16* w1t   = (u16*)(ws + 0);         // 262144 B
  u16* w2t   = (u16*)(ws + 262144);    // 131072 B
  u16* w3t   = (u16*)(ws + 393216);    // 65536 B
  u16* wpack = (u16*)(ws + 458752);    // 1572864 B
  u16* x1    = (u16*)(ws + 2031616);   // 67108864 B

  hipLaunchKernelGGL(prep_wpack, dim3(3072), dim3(256), 0, stream,
                     Wi_f, Wh_f, Wi_r, Wh_r, wpack);
  hipLaunchKernelGGL(poison_x1, dim3(8192), dim3(256), 0, stream, (uint4*)x1);
  hipLaunchKernelGGL(prep_small, dim3(896), dim3(256), 0, stream,
                     W1, W2, W3, w1t, w2t, w3t);
  {
    void* params[7];
    params[0] = (void*)&x0;
    params[1] = (void*)&wpack;
    params[2] = (void*)&bi_f;
    params[3] = (void*)&bh_f;
    params[4] = (void*)&bi_r;
    params[5] = (void*)&bh_r;
    params[6] = (void*)&x1;
    hipLaunchCooperativeKernel((const void*)lstm_kernel, dim3(256), dim3(512),
                               params, 0, stream);
  }
  hipLaunchKernelGGL(mlp_kernel, dim3(512), dim3(512), 0, stream,
                     x1, w1t, w2t, w3t, b1, b2, b3, out);
}

// Round 13
// 724.907 us; speedup vs baseline: 1.4340x; 1.4340x over previous
//
#include <hip/hip_runtime.h>

typedef unsigned short u16;
typedef unsigned long long u64;
typedef unsigned u32x4_t __attribute__((ext_vector_type(4)));
typedef _Float16 f16x8_t __attribute__((ext_vector_type(8)));
typedef short    i16x8_t __attribute__((ext_vector_type(8)));
typedef float    f32x4_t __attribute__((ext_vector_type(4)));

// force a loaded value to stay materialized in VGPRs (no remat/sinking)
#define PIN(x) asm volatile("" : "+v"(x))

// ---- helpers ---------------------------------------------------------------
static __device__ __forceinline__ u16 f2h(float f) {
  _Float16 h = (_Float16)f;  // RNE
  return __builtin_bit_cast(u16, h);
}
static __device__ __forceinline__ f32x4_t mfma16h(i16x8_t a, i16x8_t b, f32x4_t c) {
  return __builtin_amdgcn_mfma_f32_16x16x32_f16(
      __builtin_bit_cast(f16x8_t, a), __builtin_bit_cast(f16x8_t, b), c, 0, 0, 0);
}
static __device__ __forceinline__ float sigmoidf_(float x) { return 1.f / (1.f + __expf(-x)); }
static __device__ __forceinline__ float tanhf_(float x) { return 1.f - 2.f / (__expf(2.f * x) + 1.f); }

// true iff none of the four u16 lanes equals the sentinel 0x7FFF
static __device__ __forceinline__ bool no_sent(u64 v) {
  u64 x = v ^ 0x7FFF7FFF7FFF7FFFull;  // sentinel lane -> 0x0000
  return (((x - 0x0001000100010001ull) & ~x & 0x8000800080008000ull) == 0);
}
static __device__ __forceinline__ bool ok16(u32x4_t v) {
  u64 a = ((u64)v[1] << 32) | v[0];
  u64 b = ((u64)v[3] << 32) | v[2];
  return no_sent(a) && no_sent(b);
}

// blocking 16B LLC-coherent load (bypasses L1 and L2) -- v13-proven path
static __device__ __forceinline__ u32x4_t llc_load16(const u32x4_t* p) {
  u32x4_t r;
  asm volatile("global_load_dwordx4 %0, %1, off sc0 sc1\n\t"
               "s_waitcnt vmcnt(0)"
               : "=&v"(r) : "v"(p) : "memory");
  return r;
}
// 4B LLC write-through store (lands at the coherence point)
static __device__ __forceinline__ void llc_store4(unsigned* p, unsigned v) {
  asm volatile("global_store_dword %0, %1, off sc0 sc1" :: "v"(p), "v"(v) : "memory");
}

// ---- prep: LSTM weights pre-swizzled into MFMA fragment order --------------
// wpack[dir][tau][kb][lane][8]: tau = jb*4+g (jb = j-block, g = gate),
// kb in [0,12), lane = quad*16+mrow. Element e: n = g*256+jb*16+mrow,
// k = kb*32+quad*8+e; value = k<128 ? Wi[k][n] : Wh[k-128][n].
__global__ __launch_bounds__(256) void prep_wpack(const float* __restrict__ Wi_f,
                                                  const float* __restrict__ Wh_f,
                                                  const float* __restrict__ Wi_r,
                                                  const float* __restrict__ Wh_r,
                                                  u16* __restrict__ wpack) {
  int id = blockIdx.x * 256 + threadIdx.x;
  if (id >= 786432) return;  // 2*64*12*64*8
  int e = id & 7, r = id >> 3;
  int lane = r & 63; r >>= 6;
  int kb = r % 12; r /= 12;
  int tau = r & 63, dir = r >> 6;
  int mrow = lane & 15, quad = lane >> 4;
  int jb = tau >> 2, g = tau & 3;
  int n = g * 256 + jb * 16 + mrow;
  int k = kb * 32 + quad * 8 + e;
  const float* Wi = dir ? Wi_r : Wi_f;
  const float* Wh = dir ? Wh_r : Wh_f;
  float v = (k < 128) ? Wi[k * 1024 + n] : Wh[(k - 128) * 1024 + n];
  wpack[id] = f2h(v);
}

// ---- prep: poison x1 with the f16-NaN sentinel (re-run every launch) -------
// h values are sigmoid*tanh in [-1,1]; the bit pattern 0x7FFF is unreachable,
// so "!= sentinel" certifies the producer's store for this launch has landed.
__global__ __launch_bounds__(256) void poison_x1(uint4* __restrict__ x1v) {
  size_t id = (size_t)blockIdx.x * 256 + threadIdx.x;  // 2,097,152 threads
  const uint4 s = {0x7FFF7FFFu, 0x7FFF7FFFu, 0x7FFF7FFFu, 0x7FFF7FFFu};
  x1v[id * 2] = s;
  x1v[id * 2 + 1] = s;  // 32 B/thread -> 64 MB total
}

// ---- prep: MLP W^T in f16 (W1[512][256], W2[256][256], W3[256][128]) -------
__global__ __launch_bounds__(256) void prep_small(const float* __restrict__ W1,
                                                  const float* __restrict__ W2,
                                                  const float* __restrict__ W3,
                                                  u16* __restrict__ w1t,
                                                  u16* __restrict__ w2t,
                                                  u16* __restrict__ w3t) {
  int id = blockIdx.x * 256 + threadIdx.x;
  if (id < 131072) { int n = id >> 9, k = id & 511; w1t[id] = f2h(W1[k * 256 + n]); return; }
  id -= 131072;
  if (id < 65536) { int n = id >> 8, k = id & 255; w2t[id] = f2h(W2[k * 256 + n]); return; }
  id -= 65536;
  if (id < 32768) { int n = id >> 8, k = id & 255; w3t[id] = f2h(W3[k * 128 + n]); }
}

// ---- bidirectional LSTM v16: v13 protocol, 2 blocks/CU for TLP overlap -----
// v15 postmortem: L2 fast-path polling can pin a stale clean line -> dead.
// v13's LLC sentinel protocol is kept VERBATIM. The per-step LLC round-trip
// (~2-2.5us) can only be HIDDEN under an independent recurrence; v14 failed
// by serializing two groups in one instruction stream. v16 uses hardware TLP:
// 512 blocks x 256 threads, ~66 KB LDS -> TWO blocks per CU. While block A's
// waves sleep in the poll, block B's waves compute. bid->(q,dir,grp) is
// permuted so co-resident blocks (bid c, c+256 under round-robin) belong to
// DIFFERENT sync domains (grp offset 16) -> truly independent streams.
// Block = 8 taus (32 h-cols) x dir x 16-row grp; wave owns 2 taus (24 MFMA,
// same as v13). Wh kb4..9 LDS (48 KB), kb10..11 pinned regs (16 VGPR), Wi
// pinned (32 VGPR). Exchange/sentinel/barriers/MFMA order: v13-verbatim ->
// numerics bit-identical.
__global__ __launch_bounds__(256, 2) void lstm_kernel(
    const float* __restrict__ x0, const u16* __restrict__ wpack,
    const float* __restrict__ bi_f, const float* __restrict__ bh_f,
    const float* __restrict__ bi_r, const float* __restrict__ bh_r,
    u16* __restrict__ x1) {
  __shared__ __align__(16) u16 lwh[8][6][64][8];   // 48 KB Wh kb4..9, 8 taus
  __shared__ __align__(16) u16 ah[16][256];        // 8 KB h panel, XOR-swizzled
  __shared__ __align__(16) float gbuf[16][132];    // gate pre-activations (f32)

  const int tid = threadIdx.x;
  const int lane = tid & 63;
  const int w = tid >> 6;             // wave 0..3
  const int bid = blockIdx.x;
  // permuted mapping: co-resident pair (bid, bid+256) -> different grp
  const int hi = bid >> 8;            // 0..1
  const int lo = bid & 255;
  const int q = (lo >> 6) + (hi << 2);        // gate-slice 0..7 (8 taus each)
  const int dir = (lo >> 5) & 1;
  const int grp = ((lo & 31) + hi * 16) & 31;
  const int b0 = grp * 16;
  const u16* wpk = wpack + (size_t)dir * (64 * 12 * 64 * 8);
  const float* bi = dir ? bi_r : bi_f;
  const float* bh = dir ? bh_r : bh_f;
  const int mrow = lane & 15, quad = lane >> 4;
  const int tauL0 = 2 * w;            // this wave's 2 local taus

  // biases for the wave's 2 taus
  float bias2[2];
#pragma unroll
  for (int lt = 0; lt < 2; ++lt) {
    int tau_g = 8 * q + tauL0 + lt;
    int n = (tau_g & 3) * 256 + (tau_g >> 2) * 16 + mrow;
    bias2[lt] = bi[n] + bh[n];
  }

  // Wh kb4..9 for the block's 8 taus -> LDS (3072 frags of 16 B, 12/thread)
  for (int r = 0; r < 12; ++r) {
    int d = r * 256 + tid;
    int ltau = d / 384;
    int rem = d - ltau * 384;
    int lkb = rem >> 6, ll = rem & 63;
    *(i16x8_t*)&lwh[ltau][lkb][ll][0] =
        *(const i16x8_t*)(wpk + (((size_t)(8 * q + ltau) * 12 + 4 + lkb) * 64 + ll) * 8);
  }
  // Wi kb0..3 (32 VGPR) + Wh kb10..11 (16 VGPR) -> pinned registers
  i16x8_t wir[2][4], whr[2][2];
#pragma unroll
  for (int lt = 0; lt < 2; ++lt) {
#pragma unroll
    for (int kb = 0; kb < 4; ++kb) {
      wir[lt][kb] =
          *(const i16x8_t*)(wpk + (((size_t)(8 * q + tauL0 + lt) * 12 + kb) * 64 + lane) * 8);
      PIN(wir[lt][kb]);
    }
#pragma unroll
    for (int kk = 0; kk < 2; ++kk) {
      whr[lt][kk] =
          *(const i16x8_t*)(wpk + (((size_t)(8 * q + tauL0 + lt) * 12 + 10 + kk) * 64 + lane) * 8);
      PIN(whr[lt][kk]);
    }
  }
  __syncthreads();  // lwh ready

  // c-state: thread owns 2 adjacent cells (row = tid>>4, jj = 2*(tid&15)+e)
  const int crow = tid >> 4;
  const int cj0 = (tid & 15) * 2;
  float c0 = 0.f, c1 = 0.f;

  // per-lane global base for x-fragment loads (direct, pre-stage)
  const float* xfrag_base = x0 + (size_t)(b0 + mrow) * 16384 + quad * 8;
  // h staging: 32B/thread (2x16B polls), coalesced rows; LDS dst XOR-swizzled
  const int fm = tid >> 4, fj = (tid & 15) * 16;
  const int swz = (fm & 7) << 3;
  const u16* hstage_src = x1 + (size_t)(b0 + fm) * 65536 + dir * 256 + fj;
  u16* ah_dst0 = &ah[fm][fj ^ swz];
  u16* ah_dst1 = &ah[fm][(fj + 8) ^ swz];

  for (int t = 0; t < 128; ++t) {
    const int teff = dir ? 127 - t : t;

    // x fragments: direct from x0 (read-only, normal cached loads)
    i16x8_t afx[4];
    {
      const float* xp = xfrag_base + (size_t)teff * 128;
#pragma unroll
      for (int kb = 0; kb < 4; ++kb) {
        float4 va = *(const float4*)(xp + kb * 32);
        float4 vb = *(const float4*)(xp + kb * 32 + 4);
        i16x8_t v;
        v[0] = (short)f2h(va.x); v[1] = (short)f2h(va.y);
        v[2] = (short)f2h(va.z); v[3] = (short)f2h(va.w);
        v[4] = (short)f2h(vb.x); v[5] = (short)f2h(vb.y);
        v[6] = (short)f2h(vb.z); v[7] = (short)f2h(vb.w);
        afx[kb] = v;
      }
    }
    // x-projection MFMAs BEFORE staging (runs while producers finish)
    f32x4_t acc[2];
#pragma unroll
    for (int lt = 0; lt < 2; ++lt) {
      float bv = bias2[lt];
      f32x4_t a = {bv, bv, bv, bv};
      a = mfma16h(afx[0], wir[lt][0], a);
      a = mfma16h(afx[1], wir[lt][1], a);
      a = mfma16h(afx[2], wir[lt][2], a);
      a = mfma16h(afx[3], wir[lt][3], a);
      acc[lt] = a;
    }

    // stage h_{t-1}: two 16B LLC-coherent loads per thread, retry on sentinel.
    // While this block sleeps, the CU's OTHER block computes (TLP overlap).
    if (t > 0) {
      const u32x4_t* hsrc = (const u32x4_t*)(hstage_src + (size_t)(t - 1) * 512);
      u32x4_t h0 = llc_load16(hsrc);
      u32x4_t h1 = llc_load16(hsrc + 1);
      unsigned iter = 0;
      while (!(ok16(h0) && ok16(h1))) {
        __builtin_amdgcn_s_sleep(1);
        if (!ok16(h0)) h0 = llc_load16(hsrc);
        if (!ok16(h1)) h1 = llc_load16(hsrc + 1);
        if (++iter > (1u << 20)) break;  // fail-safe: bug -> wrong, not hang
      }
      *(u32x4_t*)ah_dst0 = h0;
      *(u32x4_t*)ah_dst1 = h1;
    }
    __syncthreads();  // (A) ah ready

    if (t > 0) {  // h-part MFMAs: conflict-free swizzled ds_read_b128
      i16x8_t afh[8];
#pragma unroll
      for (int kb = 0; kb < 8; ++kb)
        afh[kb] = *(const i16x8_t*)&ah[mrow][(kb * 32 + quad * 8) ^ ((mrow & 7) << 3)];
#pragma unroll
      for (int lt = 0; lt < 2; ++lt) {
#pragma unroll
        for (int kb = 0; kb < 6; ++kb)
          acc[lt] = mfma16h(afh[kb], *(const i16x8_t*)&lwh[tauL0 + lt][kb][lane][0], acc[lt]);
        acc[lt] = mfma16h(afh[6], whr[lt][0], acc[lt]);
        acc[lt] = mfma16h(afh[7], whr[lt][1], acc[lt]);
      }
    }
    // write gate pre-activations (gbuf reuse ordered by barrier A)
#pragma unroll
    for (int lt = 0; lt < 2; ++lt) {
      int col = (tauL0 + lt) * 16 + mrow;
#pragma unroll
      for (int r = 0; r < 4; ++r) gbuf[quad * 4 + r][col] = acc[lt][r];
    }
    __syncthreads();  // (B) gbuf ready

    // gate phase: 2 cells/thread; jj in [0,32): base = (jj>>4)*64 + (jj&15)
    {
      float hv[2];
#pragma unroll
      for (int e = 0; e < 2; ++e) {
        int jj = cj0 + e;
        int base = (jj >> 4) * 64 + (jj & 15);
        float fg = gbuf[crow][base];
        float ig = gbuf[crow][base + 16];
        float ag = gbuf[crow][base + 32];
        float og = gbuf[crow][base + 48];
        float cc = e ? c1 : c0;
        float cv = sigmoidf_(fg) * cc + sigmoidf_(ig) * tanhf_(ag);
        if (e) c1 = cv; else c0 = cv;
        hv[e] = sigmoidf_(og) * tanhf_(cv);
      }
      unsigned pack = (unsigned)f2h(hv[0]) | ((unsigned)f2h(hv[1]) << 16);
      unsigned* hp = (unsigned*)(x1 + ((size_t)((b0 + crow) * 128 + t)) * 512 +
                                 dir * 256 + 32 * q + cj0);
      // plain write-through to LLC; consumers certify arrival via sentinel
      llc_store4(hp, pack);
    }
    // no trailing barrier, no flag: the store IS the signal
  }
}

// ---- fused MLP + heads (unchanged — passing) ------------------------------
__global__ __launch_bounds__(512, 1) void mlp_kernel(
    const u16* __restrict__ x1, const u16* __restrict__ w1t,
    const u16* __restrict__ w2t, const u16* __restrict__ w3t,
    const float* __restrict__ b1, const float* __restrict__ b2,
    const float* __restrict__ b3, float* __restrict__ out) {
  __shared__ __align__(16) u16 X2[128][264];
  __shared__ __align__(16) u16 X3[128][264];
  const int tid = threadIdx.x;
  const int lane = tid & 63, wv = tid >> 6;
  const int mrow = lane & 15, quad = lane >> 4;
  const int r0 = blockIdx.x * 128;
  const f32x4_t zero4 = {0.f, 0.f, 0.f, 0.f};

  // stage 1: X2[128][256] = leaky(x1[128,512] @ W1 + b1)
  {
    f32x4_t acc[16];
#pragma unroll
    for (int n = 0; n < 16; ++n) acc[n] = zero4;
    for (int kb = 0; kb < 16; ++kb) {
      int k = kb * 32 + quad * 8;
      i16x8_t a = *(const i16x8_t*)(x1 + (size_t)(r0 + wv * 16 + mrow) * 512 + k);
#pragma unroll
      for (int n = 0; n < 16; ++n) {
        i16x8_t b = *(const i16x8_t*)(w1t + (n * 16 + mrow) * 512 + k);
        acc[n] = mfma16h(a, b, acc[n]);
      }
    }
#pragma unroll
    for (int n = 0; n < 16; ++n)
#pragma unroll
      for (int r = 0; r < 4; ++r) {
        int m = wv * 16 + quad * 4 + r;
        int col = n * 16 + mrow;
        float v = acc[n][r] + b1[col];
        v = v > 0.f ? v : 0.1f * v;
        X2[m][col] = f2h(v);
      }
  }
  __syncthreads();

  // stage 2: X3[128][256] = leaky(X2 @ W2 + b2), K=256
  {
    f32x4_t acc[16];
#pragma unroll
    for (int n = 0; n < 16; ++n) acc[n] = zero4;
#pragma unroll
    for (int kb = 0; kb < 8; ++kb) {
      int k = kb * 32 + quad * 8;
      i16x8_t a = *(const i16x8_t*)&X2[wv * 16 + mrow][k];
#pragma unroll
      for (int n = 0; n < 16; ++n) {
        i16x8_t b = *(const i16x8_t*)(w2t + (n * 16 + mrow) * 256 + k);
        acc[n] = mfma16h(a, b, acc[n]);
      }
    }
#pragma unroll
    for (int n = 0; n < 16; ++n)
#pragma unroll
      for (int r = 0; r < 4; ++r) {
        int m = wv * 16 + quad * 4 + r;
        int col = n * 16 + mrow;
        float v = acc[n][r] + b2[col];
        v = v > 0.f ? v : 0.1f * v;
        X3[m][col] = f2h(v);
      }
  }
  __syncthreads();

  // stage 3: XF[128][128] = X3 @ W3 + b3 (fp32; overlays dead X2)
  float (*XF)[130] = (float (*)[130]) & X2[0][0];
  {
    f32x4_t acc[8];
#pragma unroll
    for (int n = 0; n < 8; ++n) acc[n] = zero4;
#pragma unroll
    for (int kb = 0; kb < 8; ++kb) {
      int k = kb * 32 + quad * 8;
      i16x8_t a = *(const i16x8_t*)&X3[wv * 16 + mrow][k];
#pragma unroll
      for (int n = 0; n < 8; ++n) {
        i16x8_t b = *(const i16x8_t*)(w3t + (n * 16 + mrow) * 256 + k);
        acc[n] = mfma16h(a, b, acc[n]);
      }
    }
#pragma unroll
    for (int n = 0; n < 8; ++n)
#pragma unroll
      for (int r = 0; r < 4; ++r) {
        int m = wv * 16 + quad * 4 + r;
        int col = n * 16 + mrow;
        XF[m][col] = acc[n][r] + b3[col];
      }
  }
  __syncthreads();

  // heads: cols 0:64 sigmoid; softmax over [64,72), [72,88), [88,128)
  if (tid < 128) {
    int row = tid;
    float* xr = XF[row];
    float* op = out + (size_t)(r0 + row) * 128;
    for (int cc = 0; cc < 64; ++cc) op[cc] = sigmoidf_(xr[cc]);
  } else if (tid < 256) {
    int row = tid - 128;
    float* xr = XF[row];
    float* op = out + (size_t)(r0 + row) * 128;
    const int s0s[3] = {64, 72, 88};
    const int s1s[3] = {72, 88, 128};
    for (int s = 0; s < 3; ++s) {
      int s0 = s0s[s], s1 = s1s[s];
      float mx = xr[s0];
      for (int q = s0 + 1; q < s1; ++q) mx = fmaxf(mx, xr[q]);
      float sum = 0.f;
      for (int q = s0; q < s1; ++q) { float e = __expf(xr[q] - mx); xr[q] = e; sum += e; }
      float inv = 1.f / sum;
      for (int q = s0; q < s1; ++q) op[q] = xr[q] * inv;
    }
  }
}

// ---- launch ----------------------------------------------------------------
extern "C" void kernel_launch(void* const* d_in, const int* in_sizes, int n_in,
                              void* d_out, int out_size, void* d_ws, size_t ws_size,
                              hipStream_t stream) {
  const float* x0   = (const float*)d_in[0];
  const float* Wi_f = (const float*)d_in[1];
  const float* bi_f = (const float*)d_in[2];
  const float* Wh_f = (const float*)d_in[3];
  const float* bh_f = (const float*)d_in[4];
  const float* Wi_r = (const float*)d_in[5];
  const float* bi_r = (const float*)d_in[6];
  const float* Wh_r = (const float*)d_in[7];
  const float* bh_r = (const float*)d_in[8];
  const float* W1 = (const float*)d_in[9];
  const float* b1 = (const float*)d_in[10];
  const float* W2 = (const float*)d_in[11];
  const float* b2 = (const float*)d_in[12];
  const float* W3 = (const float*)d_in[13];
  const float* b3 = (const float*)d_in[14];
  float* out = (float*)d_out;

  char* ws = (char*)d_ws;
  u16* w1t   = (u16*)(ws + 0);         // 262144 B
  u16* w2t   = (u16*)(ws + 262144);    // 131072 B
  u16* w3t   = (u16*)(ws + 393216);    // 65536 B
  u16* wpack = (u16*)(ws + 458752);    // 1572864 B
  u16* x1    = (u16*)(ws + 2031616);   // 67108864 B

  hipLaunchKernelGGL(prep_wpack, dim3(3072), dim3(256), 0, stream,
                     Wi_f, Wh_f, Wi_r, Wh_r, wpack);
  hipLaunchKernelGGL(poison_x1, dim3(8192), dim3(256), 0, stream, (uint4*)x1);
  hipLaunchKernelGGL(prep_small, dim3(896), dim3(256), 0, stream,
                     W1, W2, W3, w1t, w2t, w3t);
  {
    void* params[7];
    params[0] = (void*)&x0;
    params[1] = (void*)&wpack;
    params[2] = (void*)&bi_f;
    params[3] = (void*)&bh_f;
    params[4] = (void*)&bi_r;
    params[5] = (void*)&bh_r;
    params[6] = (void*)&x1;
    hipLaunchCooperativeKernel((const void*)lstm_kernel, dim3(512), dim3(256),
                               params, 0, stream);
  }
  hipLaunchKernelGGL(mlp_kernel, dim3(512), dim3(512), 0, stream,
                     x1, w1t, w2t, w3t, b1, b2, b3, out);
}

// Round 14
// 677.619 us; speedup vs baseline: 1.5341x; 1.0698x over previous
//
#include <hip/hip_runtime.h>

typedef unsigned short u16;
typedef unsigned long long u64;
typedef unsigned u32x4_t __attribute__((ext_vector_type(4)));
typedef _Float16 f16x8_t __attribute__((ext_vector_type(8)));
typedef short    i16x8_t __attribute__((ext_vector_type(8)));
typedef float    f32x4_t __attribute__((ext_vector_type(4)));

// force a loaded value to stay materialized in VGPRs (no remat/sinking)
#define PIN(x) asm volatile("" : "+v"(x))

// ---- helpers ---------------------------------------------------------------
static __device__ __forceinline__ u16 f2h(float f) {
  _Float16 h = (_Float16)f;  // RNE
  return __builtin_bit_cast(u16, h);
}
static __device__ __forceinline__ f32x4_t mfma16h(i16x8_t a, i16x8_t b, f32x4_t c) {
  return __builtin_amdgcn_mfma_f32_16x16x32_f16(
      __builtin_bit_cast(f16x8_t, a), __builtin_bit_cast(f16x8_t, b), c, 0, 0, 0);
}
static __device__ __forceinline__ float sigmoidf_(float x) { return 1.f / (1.f + __expf(-x)); }
static __device__ __forceinline__ float tanhf_(float x) { return 1.f - 2.f / (__expf(2.f * x) + 1.f); }

// true iff none of the four u16 lanes equals the sentinel 0x7FFF
static __device__ __forceinline__ bool no_sent(u64 v) {
  u64 x = v ^ 0x7FFF7FFF7FFF7FFFull;  // sentinel lane -> 0x0000
  return (((x - 0x0001000100010001ull) & ~x & 0x8000800080008000ull) == 0);
}
static __device__ __forceinline__ bool ok16(u32x4_t v) {
  u64 a = ((u64)v[1] << 32) | v[0];
  u64 b = ((u64)v[3] << 32) | v[2];
  return no_sent(a) && no_sent(b);
}

// blocking 16B LLC-coherent load (bypasses L1 and L2) -- v13-proven path
static __device__ __forceinline__ u32x4_t llc_load16(const u32x4_t* p) {
  u32x4_t r;
  asm volatile("global_load_dwordx4 %0, %1, off sc0 sc1\n\t"
               "s_waitcnt vmcnt(0)"
               : "=&v"(r) : "v"(p) : "memory");
  return r;
}
// 4B LLC write-through store (lands at the coherence point)
static __device__ __forceinline__ void llc_store4(unsigned* p, unsigned v) {
  asm volatile("global_store_dword %0, %1, off sc0 sc1" :: "v"(p), "v"(v) : "memory");
}

// ---- merged prep: poison x1 + wpack swizzle + MLP W^T, one launch ----------
// blocks [0,8192): poison x1 with f16-NaN sentinel 0x7FFF (h in [-1,1] can
//   never produce it; "!= sentinel" certifies this launch's store landed).
// blocks [8192,11264): wpack[dir][tau][kb][lane][8], tau=jb*4+g; element e:
//   n=g*256+jb*16+mrow, k=kb*32+quad*8+e; val = k<128?Wi[k][n]:Wh[k-128][n].
// blocks [11264,12160): w1t/w2t/w3t = W^T in f16.
__global__ __launch_bounds__(256) void prep_all(
    const float* __restrict__ Wi_f, const float* __restrict__ Wh_f,
    const float* __restrict__ Wi_r, const float* __restrict__ Wh_r,
    const float* __restrict__ W1, const float* __restrict__ W2,
    const float* __restrict__ W3, u16* __restrict__ wpack,
    u16* __restrict__ w1t, u16* __restrict__ w2t, u16* __restrict__ w3t,
    uint4* __restrict__ x1v) {
  int b = blockIdx.x;
  if (b < 8192) {  // poison: 32 B/thread -> 64 MB
    size_t id = (size_t)b * 256 + threadIdx.x;
    const uint4 s = {0x7FFF7FFFu, 0x7FFF7FFFu, 0x7FFF7FFFu, 0x7FFF7FFFu};
    x1v[id * 2] = s;
    x1v[id * 2 + 1] = s;
    return;
  }
  if (b < 11264) {  // wpack
    int id = (b - 8192) * 256 + threadIdx.x;
    if (id >= 786432) return;  // 2*64*12*64*8
    int e = id & 7, r = id >> 3;
    int lane = r & 63; r >>= 6;
    int kb = r % 12; r /= 12;
    int tau = r & 63, dir = r >> 6;
    int mrow = lane & 15, quad = lane >> 4;
    int jb = tau >> 2, g = tau & 3;
    int n = g * 256 + jb * 16 + mrow;
    int k = kb * 32 + quad * 8 + e;
    const float* Wi = dir ? Wi_r : Wi_f;
    const float* Wh = dir ? Wh_r : Wh_f;
    float v = (k < 128) ? Wi[k * 1024 + n] : Wh[(k - 128) * 1024 + n];
    wpack[id] = f2h(v);
    return;
  }
  int id = (b - 11264) * 256 + threadIdx.x;
  if (id < 131072) { int n = id >> 9, k = id & 511; w1t[id] = f2h(W1[k * 256 + n]); return; }
  id -= 131072;
  if (id < 65536) { int n = id >> 8, k = id & 255; w2t[id] = f2h(W2[k * 256 + n]); return; }
  id -= 65536;
  if (id < 32768) { int n = id >> 8, k = id & 255; w3t[id] = f2h(W3[k * 128 + n]); }
}

// ---- bidirectional LSTM v17 = v13 verbatim, normal (non-cooperative) launch
// 256 blocks = q(4 gate-slices) x dir(2) x grp(32 batch-groups of 16 rows).
// Block owns gate-cols tau_g in [16q,16q+16): Wh slice (128 KB) LDS-resident,
// Wi slice in 32 pinned VGPR/wave. Sentinel h-exchange through the LLC
// (poisoned x1, plain sc0|sc1 loads/stores, per-u16 tear check). 256 blocks
// at 156 KB LDS = exactly 1/CU with the GPU otherwise idle -> all blocks
// resident under a normal launch (cooperative overhead removed); the poll
// timeout turns any residency violation into a visible wrong answer.
// Numerics bit-identical to v13 (same MFMA order, same f16 points).
__global__ __launch_bounds__(512, 2) void lstm_kernel(
    const float* __restrict__ x0, const u16* __restrict__ wpack,
    const float* __restrict__ bi_f, const float* __restrict__ bh_f,
    const float* __restrict__ bi_r, const float* __restrict__ bh_r,
    u16* __restrict__ x1) {
  __shared__ __align__(16) u16 lwh[16][8][64][8];  // 128 KB Wh kb4..11, 16 taus
  __shared__ __align__(16) u16 ah[16][256];        // 8 KB h panel, XOR-swizzled
  __shared__ __align__(16) float gbuf[16][260];    // gate pre-activations (f32)

  const int tid = threadIdx.x;
  const int lane = tid & 63;
  const int w = tid >> 6;             // wave 0..7
  const int bid = blockIdx.x;
  const int q = bid >> 6;             // gate-slice 0..3
  const int rem = bid & 63;
  const int dir = rem >> 5;
  const int grp = rem & 31;
  const int b0 = grp * 16;
  const u16* wpk = wpack + (size_t)dir * (64 * 12 * 64 * 8);
  const float* bi = dir ? bi_r : bi_f;
  const float* bh = dir ? bh_r : bh_f;
  const int mrow = lane & 15, quad = lane >> 4;
  const int tauL0 = 2 * w;            // this wave's 2 local n-tiles

  // biases for the wave's 2 taus
  float bias2[2];
#pragma unroll
  for (int lt = 0; lt < 2; ++lt) {
    int tau_g = 16 * q + tauL0 + lt;
    int n = (tau_g & 3) * 256 + (tau_g >> 2) * 16 + mrow;
    bias2[lt] = bi[n] + bh[n];
  }

  // Wh kb4..11 for the block's 16 taus -> LDS (8192 frags of 16 B)
#pragma unroll
  for (int r = 0; r < 16; ++r) {
    int d = r * 512 + tid;
    int ltau = d >> 9, lkb = (d >> 6) & 7, ll = d & 63;
    *(i16x8_t*)&lwh[ltau][lkb][ll][0] =
        *(const i16x8_t*)(wpk + (((size_t)(16 * q + ltau) * 12 + 4 + lkb) * 64 + ll) * 8);
  }
  // Wi kb0..3 for the wave's 2 taus -> registers (32 VGPR), pinned
  i16x8_t wir[2][4];
#pragma unroll
  for (int lt = 0; lt < 2; ++lt)
#pragma unroll
    for (int kb = 0; kb < 4; ++kb) {
      wir[lt][kb] =
          *(const i16x8_t*)(wpk + (((size_t)(16 * q + tauL0 + lt) * 12 + kb) * 64 + lane) * 8);
      PIN(wir[lt][kb]);
    }
  __syncthreads();  // lwh ready

  // c-state: thread owns 2 adjacent cells (row = tid>>5, jj = 2*(tid&31)+e)
  const int crow = tid >> 5;
  const int cj0 = (tid & 31) * 2;
  float c0 = 0.f, c1 = 0.f;

  // per-lane global base for x-fragment loads (direct, pre-stage)
  const float* xfrag_base = x0 + (size_t)(b0 + mrow) * 16384 + quad * 8;
  // h staging: 16B/thread, coalesced rows; LDS dst is XOR-swizzled
  const int fm = tid >> 5, fj = (tid & 31) * 8;
  const u16* hstage_src = x1 + (size_t)(b0 + fm) * 65536 + dir * 256 + fj;
  u16* ah_dst = &ah[fm][fj ^ ((fm & 7) << 3)];

  for (int t = 0; t < 128; ++t) {
    const int teff = dir ? 127 - t : t;

    // x fragments: direct from x0 (read-only, normal cached loads)
    i16x8_t afx[4];
    {
      const float* xp = xfrag_base + (size_t)teff * 128;
#pragma unroll
      for (int kb = 0; kb < 4; ++kb) {
        float4 va = *(const float4*)(xp + kb * 32);
        float4 vb = *(const float4*)(xp + kb * 32 + 4);
        i16x8_t v;
        v[0] = (short)f2h(va.x); v[1] = (short)f2h(va.y);
        v[2] = (short)f2h(va.z); v[3] = (short)f2h(va.w);
        v[4] = (short)f2h(vb.x); v[5] = (short)f2h(vb.y);
        v[6] = (short)f2h(vb.z); v[7] = (short)f2h(vb.w);
        afx[kb] = v;
      }
    }
    // x-projection MFMAs BEFORE staging (overlap with producers finishing)
    f32x4_t acc[2];
#pragma unroll
    for (int lt = 0; lt < 2; ++lt) {
      float bv = bias2[lt];
      f32x4_t a = {bv, bv, bv, bv};
      a = mfma16h(afx[0], wir[lt][0], a);
      a = mfma16h(afx[1], wir[lt][1], a);
      a = mfma16h(afx[2], wir[lt][2], a);
      a = mfma16h(afx[3], wir[lt][3], a);
      acc[lt] = a;
    }

    // stage h_{t-1}: one 16B LLC-coherent load per thread, retry on sentinel.
    // ah overwrite is safe: all afh reads of step t-1 precede barrier B(t-1),
    // and this stage follows B(t-1) in program order on every thread.
    if (t > 0) {
      const u32x4_t* hsrc = (const u32x4_t*)(hstage_src + (size_t)(t - 1) * 512);
      u32x4_t hv4 = llc_load16(hsrc);
      unsigned iter = 0;
      while (!ok16(hv4)) {
        __builtin_amdgcn_s_sleep(1);
        hv4 = llc_load16(hsrc);
        if (++iter > (1u << 20)) break;  // fail-safe: bug -> wrong, not hang
      }
      *(u32x4_t*)ah_dst = hv4;
    }
    __syncthreads();  // (A) ah ready

    if (t > 0) {  // h-part MFMAs: conflict-free swizzled ds_read_b128
      i16x8_t afh[8];
#pragma unroll
      for (int kb = 0; kb < 8; ++kb)
        afh[kb] = *(const i16x8_t*)&ah[mrow][(kb * 32 + quad * 8) ^ ((mrow & 7) << 3)];
#pragma unroll
      for (int lt = 0; lt < 2; ++lt) {
#pragma unroll
        for (int kb = 0; kb < 8; ++kb)
          acc[lt] = mfma16h(afh[kb], *(const i16x8_t*)&lwh[tauL0 + lt][kb][lane][0], acc[lt]);
      }
    }
    // write gate pre-activations. gbuf overwrite is safe: all gate reads of
    // step t-1 precede barrier A(t) (gate -> stage -> A in program order).
#pragma unroll
    for (int lt = 0; lt < 2; ++lt) {
      int col = (tauL0 + lt) * 16 + mrow;
#pragma unroll
      for (int r = 0; r < 4; ++r) gbuf[quad * 4 + r][col] = acc[lt][r];
    }
    __syncthreads();  // (B) gbuf ready

    // gate phase: 2 cells/thread; col(g) = jb_l*64 + g*16 + mr
    {
      float hv[2];
#pragma unroll
      for (int e = 0; e < 2; ++e) {
        int jj = cj0 + e;
        int base = (jj >> 4) * 64 + (jj & 15);
        float fg = gbuf[crow][base];
        float ig = gbuf[crow][base + 16];
        float ag = gbuf[crow][base + 32];
        float og = gbuf[crow][base + 48];
        float cc = e ? c1 : c0;
        float cv = sigmoidf_(fg) * cc + sigmoidf_(ig) * tanhf_(ag);
        if (e) c1 = cv; else c0 = cv;
        hv[e] = sigmoidf_(og) * tanhf_(cv);
      }
      unsigned pack = (unsigned)f2h(hv[0]) | ((unsigned)f2h(hv[1]) << 16);
      unsigned* hp = (unsigned*)(x1 + ((size_t)((b0 + crow) * 128 + t)) * 512 +
                                 dir * 256 + 64 * q + cj0);
      // plain write-through to LLC; consumers certify arrival via sentinel
      llc_store4(hp, pack);
    }
    // no trailing barrier, no flag: the store IS the signal
  }
}

// ---- fused MLP + heads: 64-row blocks, 2 blocks/CU, parallel heads ---------
// Same math and per-row accumulation order as the proven 128-row version
// (absmax-identical); only the row tiling (64/block, 1024 blocks, 256 thr,
// 67 KB LDS -> 2 blocks/CU) and head-phase parallelization changed.
__global__ __launch_bounds__(256, 2) void mlp_kernel(
    const u16* __restrict__ x1, const u16* __restrict__ w1t,
    const u16* __restrict__ w2t, const u16* __restrict__ w3t,
    const float* __restrict__ b1, const float* __restrict__ b2,
    const float* __restrict__ b3, float* __restrict__ out) {
  __shared__ __align__(16) u16 X2[64][264];
  __shared__ __align__(16) u16 X3[64][264];
  const int tid = threadIdx.x;
  const int lane = tid & 63, wv = tid >> 6;   // wave 0..3, rows wv*16..+16
  const int mrow = lane & 15, quad = lane >> 4;
  const int r0 = blockIdx.x * 64;
  const f32x4_t zero4 = {0.f, 0.f, 0.f, 0.f};

  // stage 1: X2[64][256] = leaky(x1[64,512] @ W1 + b1)
  {
    f32x4_t acc[16];
#pragma unroll
    for (int n = 0; n < 16; ++n) acc[n] = zero4;
    for (int kb = 0; kb < 16; ++kb) {
      int k = kb * 32 + quad * 8;
      i16x8_t a = *(const i16x8_t*)(x1 + (size_t)(r0 + wv * 16 + mrow) * 512 + k);
#pragma unroll
      for (int n = 0; n < 16; ++n) {
        i16x8_t b = *(const i16x8_t*)(w1t + (n * 16 + mrow) * 512 + k);
        acc[n] = mfma16h(a, b, acc[n]);
      }
    }
#pragma unroll
    for (int n = 0; n < 16; ++n)
#pragma unroll
      for (int r = 0; r < 4; ++r) {
        int m = wv * 16 + quad * 4 + r;
        int col = n * 16 + mrow;
        float v = acc[n][r] + b1[col];
        v = v > 0.f ? v : 0.1f * v;
        X2[m][col] = f2h(v);
      }
  }
  __syncthreads();

  // stage 2: X3[64][256] = leaky(X2 @ W2 + b2), K=256
  {
    f32x4_t acc[16];
#pragma unroll
    for (int n = 0; n < 16; ++n) acc[n] = zero4;
#pragma unroll
    for (int kb = 0; kb < 8; ++kb) {
      int k = kb * 32 + quad * 8;
      i16x8_t a = *(const i16x8_t*)&X2[wv * 16 + mrow][k];
#pragma unroll
      for (int n = 0; n < 16; ++n) {
        i16x8_t b = *(const i16x8_t*)(w2t + (n * 16 + mrow) * 256 + k);
        acc[n] = mfma16h(a, b, acc[n]);
      }
    }
#pragma unroll
    for (int n = 0; n < 16; ++n)
#pragma unroll
      for (int r = 0; r < 4; ++r) {
        int m = wv * 16 + quad * 4 + r;
        int col = n * 16 + mrow;
        float v = acc[n][r] + b2[col];
        v = v > 0.f ? v : 0.1f * v;
        X3[m][col] = f2h(v);
      }
  }
  __syncthreads();

  // stage 3: XF[64][128] = X3 @ W3 + b3 (fp32; overlays dead X2)
  float (*XF)[130] = (float (*)[130]) & X2[0][0];  // 64*130*4 = 33.3 KB <= X2
  {
    f32x4_t acc[8];
#pragma unroll
    for (int n = 0; n < 8; ++n) acc[n] = zero4;
#pragma unroll
    for (int kb = 0; kb < 8; ++kb) {
      int k = kb * 32 + quad * 8;
      i16x8_t a = *(const i16x8_t*)&X3[wv * 16 + mrow][k];
#pragma unroll
      for (int n = 0; n < 8; ++n) {
        i16x8_t b = *(const i16x8_t*)(w3t + (n * 16 + mrow) * 256 + k);
        acc[n] = mfma16h(a, b, acc[n]);
      }
    }
#pragma unroll
    for (int n = 0; n < 8; ++n)
#pragma unroll
      for (int r = 0; r < 4; ++r) {
        int m = wv * 16 + quad * 4 + r;
        int col = n * 16 + mrow;
        XF[m][col] = acc[n][r] + b3[col];
      }
  }
  __syncthreads();

  // heads (parallel): sigmoid cols 0:64 -> 16 elems/thread;
  // softmax segs [64,72),[72,88),[88,128) -> one (row,seg) task/thread.
  {
    for (int i = 0; i < 16; ++i) {
      int idx = tid * 16 + i;          // 4096 = 64 rows x 64 cols
      int row = idx >> 6, cc = idx & 63;
      out[(size_t)(r0 + row) * 128 + cc] = sigmoidf_(XF[row][cc]);
    }
    if (tid < 192) {
      int row = tid >> 2;              // uses 3 of every 4 slots
      int s = tid & 3;
      if (s < 3) {
        const int s0s[3] = {64, 72, 88};
        const int s1s[3] = {72, 88, 128};
        int s0 = s0s[s], s1 = s1s[s];
        float* xr = XF[row];
        float* op = out + (size_t)(r0 + row) * 128;
        float mx = xr[s0];
        for (int qq = s0 + 1; qq < s1; ++qq) mx = fmaxf(mx, xr[qq]);
        float sum = 0.f;
        for (int qq = s0; qq < s1; ++qq) { float e = __expf(xr[qq] - mx); xr[qq] = e; sum += e; }
        float inv = 1.f / sum;
        for (int qq = s0; qq < s1; ++qq) op[qq] = xr[qq] * inv;
      }
    } else if (tid < 224) {
      int row = 48 + (tid - 192);      // rows 48..63, seg handled below
    }
  }
  // rows 48..63 seg coverage: tid>>2 covers rows 0..47 only (192 threads /4).
  // Handle rows 48..63 with threads 224..255 + 192..223 (32+32 = 48 tasks).
  {
    int tsk = -1;
    if (tid >= 224) tsk = (tid - 224);            // 0..31
    else if (tid >= 192) tsk = 32 + (tid - 192);  // 32..63 (need 48)
    if (tsk >= 0 && tsk < 48) {
      int row = 48 + tsk / 3;
      int s = tsk % 3;
      const int s0s[3] = {64, 72, 88};
      const int s1s[3] = {72, 88, 128};
      int s0 = s0s[s], s1 = s1s[s];
      float* xr = XF[row];
      float* op = out + (size_t)(r0 + row) * 128;
      float mx = xr[s0];
      for (int qq = s0 + 1; qq < s1; ++qq) mx = fmaxf(mx, xr[qq]);
      float sum = 0.f;
      for (int qq = s0; qq < s1; ++qq) { float e = __expf(xr[qq] - mx); xr[qq] = e; sum += e; }
      float inv = 1.f / sum;
      for (int qq = s0; qq < s1; ++qq) op[qq] = xr[qq] * inv;
    }
  }
}

// ---- launch ----------------------------------------------------------------
extern "C" void kernel_launch(void* const* d_in, const int* in_sizes, int n_in,
                              void* d_out, int out_size, void* d_ws, size_t ws_size,
                              hipStream_t stream) {
  const float* x0   = (const float*)d_in[0];
  const float* Wi_f = (const float*)d_in[1];
  const float* bi_f = (const float*)d_in[2];
  const float* Wh_f = (const float*)d_in[3];
  const float* bh_f = (const float*)d_in[4];
  const float* Wi_r = (const float*)d_in[5];
  const float* bi_r = (const float*)d_in[6];
  const float* Wh_r = (const float*)d_in[7];
  const float* bh_r = (const float*)d_in[8];
  const float* W1 = (const float*)d_in[9];
  const float* b1 = (const float*)d_in[10];
  const float* W2 = (const float*)d_in[11];
  const float* b2 = (const float*)d_in[12];
  const float* W3 = (const float*)d_in[13];
  const float* b3 = (const float*)d_in[14];
  float* out = (float*)d_out;

  char* ws = (char*)d_ws;
  u16* w1t   = (u16*)(ws + 0);         // 262144 B
  u16* w2t   = (u16*)(ws + 262144);    // 131072 B
  u16* w3t   = (u16*)(ws + 393216);    // 65536 B
  u16* wpack = (u16*)(ws + 458752);    // 1572864 B
  u16* x1    = (u16*)(ws + 2031616);   // 67108864 B

  hipLaunchKernelGGL(prep_all, dim3(12160), dim3(256), 0, stream,
                     Wi_f, Wh_f, Wi_r, Wh_r, W1, W2, W3,
                     wpack, w1t, w2t, w3t, (uint4*)x1);
  hipLaunchKernelGGL(lstm_kernel, dim3(256), dim3(512), 0, stream,
                     x0, wpack, bi_f, bh_f, bi_r, bh_r, x1);
  hipLaunchKernelGGL(mlp_kernel, dim3(1024), dim3(256), 0, stream,
                     x1, w1t, w2t, w3t, b1, b2, b3, out);
}

// Round 16
// 676.973 us; speedup vs baseline: 1.5355x; 1.0010x over previous
//
#include <hip/hip_runtime.h>

typedef unsigned short u16;
typedef unsigned long long u64;
typedef unsigned u32x4_t __attribute__((ext_vector_type(4)));
typedef _Float16 f16x8_t __attribute__((ext_vector_type(8)));
typedef short    i16x8_t __attribute__((ext_vector_type(8)));
typedef float    f32x4_t __attribute__((ext_vector_type(4)));

// force a loaded value to stay materialized in VGPRs (no remat/sinking)
#define PIN(x) asm volatile("" : "+v"(x))

// ---- helpers ---------------------------------------------------------------
static __device__ __forceinline__ u16 f2h(float f) {
  _Float16 h = (_Float16)f;  // RNE
  return __builtin_bit_cast(u16, h);
}
static __device__ __forceinline__ f32x4_t mfma16h(i16x8_t a, i16x8_t b, f32x4_t c) {
  return __builtin_amdgcn_mfma_f32_16x16x32_f16(
      __builtin_bit_cast(f16x8_t, a), __builtin_bit_cast(f16x8_t, b), c, 0, 0, 0);
}
static __device__ __forceinline__ float sigmoidf_(float x) { return 1.f / (1.f + __expf(-x)); }
static __device__ __forceinline__ float tanhf_(float x) { return 1.f - 2.f / (__expf(2.f * x) + 1.f); }

// true iff none of the four u16 lanes equals the sentinel 0x7FFF
static __device__ __forceinline__ bool no_sent(u64 v) {
  u64 x = v ^ 0x7FFF7FFF7FFF7FFFull;  // sentinel lane -> 0x0000
  return (((x - 0x0001000100010001ull) & ~x & 0x8000800080008000ull) == 0);
}
static __device__ __forceinline__ bool ok16(u32x4_t v) {
  u64 a = ((u64)v[1] << 32) | v[0];
  u64 b = ((u64)v[3] << 32) | v[2];
  return no_sent(a) && no_sent(b);
}

// blocking 16B LLC-coherent load (bypasses L1 and L2) -- v13-proven path
static __device__ __forceinline__ u32x4_t llc_load16(const u32x4_t* p) {
  u32x4_t r;
  asm volatile("global_load_dwordx4 %0, %1, off sc0 sc1\n\t"
               "s_waitcnt vmcnt(0)"
               : "=&v"(r) : "v"(p) : "memory");
  return r;
}
// 4B LLC write-through store (lands at the coherence point)
static __device__ __forceinline__ void llc_store4(unsigned* p, unsigned v) {
  asm volatile("global_store_dword %0, %1, off sc0 sc1" :: "v"(p), "v"(v) : "memory");
}

// ---- merged prep: poison x1 + wpack swizzle + MLP W^T, one launch ----------
// blocks [0,8192): poison x1 with f16-NaN sentinel 0x7FFF (h in [-1,1] can
//   never produce it; "!= sentinel" certifies this launch's store landed).
// blocks [8192,11264): wpack[dir][tau][kb][lane][8], tau=jb*4+g; element e:
//   n=g*256+jb*16+mrow, k=kb*32+quad*8+e; val = k<128?Wi[k][n]:Wh[k-128][n].
// blocks [11264,12160): w1t/w2t/w3t = W^T in f16.
__global__ __launch_bounds__(256) void prep_all(
    const float* __restrict__ Wi_f, const float* __restrict__ Wh_f,
    const float* __restrict__ Wi_r, const float* __restrict__ Wh_r,
    const float* __restrict__ W1, const float* __restrict__ W2,
    const float* __restrict__ W3, u16* __restrict__ wpack,
    u16* __restrict__ w1t, u16* __restrict__ w2t, u16* __restrict__ w3t,
    uint4* __restrict__ x1v) {
  int b = blockIdx.x;
  if (b < 8192) {  // poison: 32 B/thread -> 64 MB
    size_t id = (size_t)b * 256 + threadIdx.x;
    const uint4 s = {0x7FFF7FFFu, 0x7FFF7FFFu, 0x7FFF7FFFu, 0x7FFF7FFFu};
    x1v[id * 2] = s;
    x1v[id * 2 + 1] = s;
    return;
  }
  if (b < 11264) {  // wpack
    int id = (b - 8192) * 256 + threadIdx.x;
    if (id >= 786432) return;  // 2*64*12*64*8
    int e = id & 7, r = id >> 3;
    int lane = r & 63; r >>= 6;
    int kb = r % 12; r /= 12;
    int tau = r & 63, dir = r >> 6;
    int mrow = lane & 15, quad = lane >> 4;
    int jb = tau >> 2, g = tau & 3;
    int n = g * 256 + jb * 16 + mrow;
    int k = kb * 32 + quad * 8 + e;
    const float* Wi = dir ? Wi_r : Wi_f;
    const float* Wh = dir ? Wh_r : Wh_f;
    float v = (k < 128) ? Wi[k * 1024 + n] : Wh[(k - 128) * 1024 + n];
    wpack[id] = f2h(v);
    return;
  }
  int id = (b - 11264) * 256 + threadIdx.x;
  if (id < 131072) { int n = id >> 9, k = id & 511; w1t[id] = f2h(W1[k * 256 + n]); return; }
  id -= 131072;
  if (id < 65536) { int n = id >> 8, k = id & 255; w2t[id] = f2h(W2[k * 256 + n]); return; }
  id -= 65536;
  if (id < 32768) { int n = id >> 8, k = id & 255; w3t[id] = f2h(W3[k * 128 + n]); }
}

// ---- bidirectional LSTM v17/v18 = v13 verbatim, normal launch --------------
// 256 blocks = q(4 gate-slices) x dir(2) x grp(32 batch-groups of 16 rows).
// Block owns gate-cols tau_g in [16q,16q+16): Wh slice (128 KB) LDS-resident,
// Wi slice in 32 pinned VGPR/wave. Sentinel h-exchange through the LLC
// (poisoned x1, plain sc0|sc1 loads/stores, per-u16 tear check). 256 blocks
// at 156 KB LDS = exactly 1/CU with the GPU otherwise idle -> all blocks
// resident under a normal launch; the poll timeout turns any residency
// violation into a visible wrong answer. Plateau: one LLC store->detect
// round-trip per step (proven irreducible: v12/v13/v15/v16 all ~478).
__global__ __launch_bounds__(512, 2) void lstm_kernel(
    const float* __restrict__ x0, const u16* __restrict__ wpack,
    const float* __restrict__ bi_f, const float* __restrict__ bh_f,
    const float* __restrict__ bi_r, const float* __restrict__ bh_r,
    u16* __restrict__ x1) {
  __shared__ __align__(16) u16 lwh[16][8][64][8];  // 128 KB Wh kb4..11, 16 taus
  __shared__ __align__(16) u16 ah[16][256];        // 8 KB h panel, XOR-swizzled
  __shared__ __align__(16) float gbuf[16][260];    // gate pre-activations (f32)

  const int tid = threadIdx.x;
  const int lane = tid & 63;
  const int w = tid >> 6;             // wave 0..7
  const int bid = blockIdx.x;
  const int q = bid >> 6;             // gate-slice 0..3
  const int rem = bid & 63;
  const int dir = rem >> 5;
  const int grp = rem & 31;
  const int b0 = grp * 16;
  const u16* wpk = wpack + (size_t)dir * (64 * 12 * 64 * 8);
  const float* bi = dir ? bi_r : bi_f;
  const float* bh = dir ? bh_r : bh_f;
  const int mrow = lane & 15, quad = lane >> 4;
  const int tauL0 = 2 * w;            // this wave's 2 local n-tiles

  // biases for the wave's 2 taus
  float bias2[2];
#pragma unroll
  for (int lt = 0; lt < 2; ++lt) {
    int tau_g = 16 * q + tauL0 + lt;
    int n = (tau_g & 3) * 256 + (tau_g >> 2) * 16 + mrow;
    bias2[lt] = bi[n] + bh[n];
  }

  // Wh kb4..11 for the block's 16 taus -> LDS (8192 frags of 16 B)
#pragma unroll
  for (int r = 0; r < 16; ++r) {
    int d = r * 512 + tid;
    int ltau = d >> 9, lkb = (d >> 6) & 7, ll = d & 63;
    *(i16x8_t*)&lwh[ltau][lkb][ll][0] =
        *(const i16x8_t*)(wpk + (((size_t)(16 * q + ltau) * 12 + 4 + lkb) * 64 + ll) * 8);
  }
  // Wi kb0..3 for the wave's 2 taus -> registers (32 VGPR), pinned
  i16x8_t wir[2][4];
#pragma unroll
  for (int lt = 0; lt < 2; ++lt)
#pragma unroll
    for (int kb = 0; kb < 4; ++kb) {
      wir[lt][kb] =
          *(const i16x8_t*)(wpk + (((size_t)(16 * q + tauL0 + lt) * 12 + kb) * 64 + lane) * 8);
      PIN(wir[lt][kb]);
    }
  __syncthreads();  // lwh ready

  // c-state: thread owns 2 adjacent cells (row = tid>>5, jj = 2*(tid&31)+e)
  const int crow = tid >> 5;
  const int cj0 = (tid & 31) * 2;
  float c0 = 0.f, c1 = 0.f;

  // per-lane global base for x-fragment loads (direct, pre-stage)
  const float* xfrag_base = x0 + (size_t)(b0 + mrow) * 16384 + quad * 8;
  // h staging: 16B/thread, coalesced rows; LDS dst is XOR-swizzled
  const int fm = tid >> 5, fj = (tid & 31) * 8;
  const u16* hstage_src = x1 + (size_t)(b0 + fm) * 65536 + dir * 256 + fj;
  u16* ah_dst = &ah[fm][fj ^ ((fm & 7) << 3)];

  for (int t = 0; t < 128; ++t) {
    const int teff = dir ? 127 - t : t;

    // x fragments: direct from x0 (read-only, normal cached loads)
    i16x8_t afx[4];
    {
      const float* xp = xfrag_base + (size_t)teff * 128;
#pragma unroll
      for (int kb = 0; kb < 4; ++kb) {
        float4 va = *(const float4*)(xp + kb * 32);
        float4 vb = *(const float4*)(xp + kb * 32 + 4);
        i16x8_t v;
        v[0] = (short)f2h(va.x); v[1] = (short)f2h(va.y);
        v[2] = (short)f2h(va.z); v[3] = (short)f2h(va.w);
        v[4] = (short)f2h(vb.x); v[5] = (short)f2h(vb.y);
        v[6] = (short)f2h(vb.z); v[7] = (short)f2h(vb.w);
        afx[kb] = v;
      }
    }
    // x-projection MFMAs BEFORE staging (overlap with producers finishing)
    f32x4_t acc[2];
#pragma unroll
    for (int lt = 0; lt < 2; ++lt) {
      float bv = bias2[lt];
      f32x4_t a = {bv, bv, bv, bv};
      a = mfma16h(afx[0], wir[lt][0], a);
      a = mfma16h(afx[1], wir[lt][1], a);
      a = mfma16h(afx[2], wir[lt][2], a);
      a = mfma16h(afx[3], wir[lt][3], a);
      acc[lt] = a;
    }

    // stage h_{t-1}: one 16B LLC-coherent load per thread, retry on sentinel.
    // ah overwrite is safe: all afh reads of step t-1 precede barrier B(t-1),
    // and this stage follows B(t-1) in program order on every thread.
    if (t > 0) {
      const u32x4_t* hsrc = (const u32x4_t*)(hstage_src + (size_t)(t - 1) * 512);
      u32x4_t hv4 = llc_load16(hsrc);
      unsigned iter = 0;
      while (!ok16(hv4)) {
        __builtin_amdgcn_s_sleep(1);
        hv4 = llc_load16(hsrc);
        if (++iter > (1u << 20)) break;  // fail-safe: bug -> wrong, not hang
      }
      *(u32x4_t*)ah_dst = hv4;
    }
    __syncthreads();  // (A) ah ready

    if (t > 0) {  // h-part MFMAs: conflict-free swizzled ds_read_b128
      i16x8_t afh[8];
#pragma unroll
      for (int kb = 0; kb < 8; ++kb)
        afh[kb] = *(const i16x8_t*)&ah[mrow][(kb * 32 + quad * 8) ^ ((mrow & 7) << 3)];
#pragma unroll
      for (int lt = 0; lt < 2; ++lt) {
#pragma unroll
        for (int kb = 0; kb < 8; ++kb)
          acc[lt] = mfma16h(afh[kb], *(const i16x8_t*)&lwh[tauL0 + lt][kb][lane][0], acc[lt]);
      }
    }
    // write gate pre-activations. gbuf overwrite is safe: all gate reads of
    // step t-1 precede barrier A(t) (gate -> stage -> A in program order).
#pragma unroll
    for (int lt = 0; lt < 2; ++lt) {
      int col = (tauL0 + lt) * 16 + mrow;
#pragma unroll
      for (int r = 0; r < 4; ++r) gbuf[quad * 4 + r][col] = acc[lt][r];
    }
    __syncthreads();  // (B) gbuf ready

    // gate phase: 2 cells/thread; col(g) = jb_l*64 + g*16 + mr
    {
      float hv[2];
#pragma unroll
      for (int e = 0; e < 2; ++e) {
        int jj = cj0 + e;
        int base = (jj >> 4) * 64 + (jj & 15);
        float fg = gbuf[crow][base];
        float ig = gbuf[crow][base + 16];
        float ag = gbuf[crow][base + 32];
        float og = gbuf[crow][base + 48];
        float cc = e ? c1 : c0;
        float cv = sigmoidf_(fg) * cc + sigmoidf_(ig) * tanhf_(ag);
        if (e) c1 = cv; else c0 = cv;
        hv[e] = sigmoidf_(og) * tanhf_(cv);
      }
      unsigned pack = (unsigned)f2h(hv[0]) | ((unsigned)f2h(hv[1]) << 16);
      unsigned* hp = (unsigned*)(x1 + ((size_t)((b0 + crow) * 128 + t)) * 512 +
                                 dir * 256 + 64 * q + cj0);
      // plain write-through to LLC; consumers certify arrival via sentinel
      llc_store4(hp, pack);
    }
    // no trailing barrier, no flag: the store IS the signal
  }
}

// ---- fused MLP + heads v18: 64-row x 512-thread blocks, 2 blocks/CU --------
// 8 waves = 4 row-groups x 2 N-halves: per-wave B-fragment loads halve and
// waves/CU double (16) vs the 256-thread version -> latency-bound weight
// streams get 2x the TLP. Per-(row,col) kb-loop order and fragment contents
// identical to the proven version -> bit-identical output.
__global__ __launch_bounds__(512, 2) void mlp_kernel(
    const u16* __restrict__ x1, const u16* __restrict__ w1t,
    const u16* __restrict__ w2t, const u16* __restrict__ w3t,
    const float* __restrict__ b1, const float* __restrict__ b2,
    const float* __restrict__ b3, float* __restrict__ out) {
  __shared__ __align__(16) u16 X2[64][264];
  __shared__ __align__(16) u16 X3[64][264];
  const int tid = threadIdx.x;
  const int lane = tid & 63;
  const int wv = tid >> 6;                 // wave 0..7
  const int rw = wv & 3;                   // row-group (16 rows)
  const int nh = wv >> 2;                  // N-half 0..1
  const int mrow = lane & 15, quad = lane >> 4;
  const int r0 = blockIdx.x * 64;
  const f32x4_t zero4 = {0.f, 0.f, 0.f, 0.f};

  // stage 1: X2[64][256] = leaky(x1[64,512] @ W1 + b1); wave does 8 n-tiles
  {
    f32x4_t acc[8];
#pragma unroll
    for (int n = 0; n < 8; ++n) acc[n] = zero4;
    for (int kb = 0; kb < 16; ++kb) {
      int k = kb * 32 + quad * 8;
      i16x8_t a = *(const i16x8_t*)(x1 + (size_t)(r0 + rw * 16 + mrow) * 512 + k);
#pragma unroll
      for (int n = 0; n < 8; ++n) {
        i16x8_t b = *(const i16x8_t*)(w1t + ((nh * 8 + n) * 16 + mrow) * 512 + k);
        acc[n] = mfma16h(a, b, acc[n]);
      }
    }
#pragma unroll
    for (int n = 0; n < 8; ++n)
#pragma unroll
      for (int r = 0; r < 4; ++r) {
        int m = rw * 16 + quad * 4 + r;
        int col = (nh * 8 + n) * 16 + mrow;
        float v = acc[n][r] + b1[col];
        v = v > 0.f ? v : 0.1f * v;
        X2[m][col] = f2h(v);
      }
  }
  __syncthreads();

  // stage 2: X3[64][256] = leaky(X2 @ W2 + b2), K=256
  {
    f32x4_t acc[8];
#pragma unroll
    for (int n = 0; n < 8; ++n) acc[n] = zero4;
#pragma unroll
    for (int kb = 0; kb < 8; ++kb) {
      int k = kb * 32 + quad * 8;
      i16x8_t a = *(const i16x8_t*)&X2[rw * 16 + mrow][k];
#pragma unroll
      for (int n = 0; n < 8; ++n) {
        i16x8_t b = *(const i16x8_t*)(w2t + ((nh * 8 + n) * 16 + mrow) * 256 + k);
        acc[n] = mfma16h(a, b, acc[n]);
      }
    }
#pragma unroll
    for (int n = 0; n < 8; ++n)
#pragma unroll
      for (int r = 0; r < 4; ++r) {
        int m = rw * 16 + quad * 4 + r;
        int col = (nh * 8 + n) * 16 + mrow;
        float v = acc[n][r] + b2[col];
        v = v > 0.f ? v : 0.1f * v;
        X3[m][col] = f2h(v);
      }
  }
  __syncthreads();

  // stage 3: XF[64][128] = X3 @ W3 + b3 (fp32; overlays dead X2)
  float (*XF)[130] = (float (*)[130]) & X2[0][0];  // 64*130*4 = 33.3 KB <= X2
  {
    f32x4_t acc[4];
#pragma unroll
    for (int n = 0; n < 4; ++n) acc[n] = zero4;
#pragma unroll
    for (int kb = 0; kb < 8; ++kb) {
      int k = kb * 32 + quad * 8;
      i16x8_t a = *(const i16x8_t*)&X3[rw * 16 + mrow][k];
#pragma unroll
      for (int n = 0; n < 4; ++n) {
        i16x8_t b = *(const i16x8_t*)(w3t + ((nh * 4 + n) * 16 + mrow) * 256 + k);
        acc[n] = mfma16h(a, b, acc[n]);
      }
    }
#pragma unroll
    for (int n = 0; n < 4; ++n)
#pragma unroll
      for (int r = 0; r < 4; ++r) {
        int m = rw * 16 + quad * 4 + r;
        int col = (nh * 4 + n) * 16 + mrow;
        XF[m][col] = acc[n][r] + b3[col];
      }
  }
  __syncthreads();

  // heads (parallel, 512 threads): sigmoid 4096 elems -> 8/thread;
  // softmax: 192 (row,seg) tasks -> one per thread (tid<192).
  for (int i = 0; i < 8; ++i) {
    int idx = tid * 8 + i;              // 4096 = 64 rows x 64 cols
    int row = idx >> 6, cc = idx & 63;
    out[(size_t)(r0 + row) * 128 + cc] = sigmoidf_(XF[row][cc]);
  }
  if (tid < 192) {
    int row = tid / 3;
    int s = tid % 3;
    const int s0s[3] = {64, 72, 88};
    const int s1s[3] = {72, 88, 128};
    int s0 = s0s[s], s1 = s1s[s];
    float* xr = XF[row];
    float* op = out + (size_t)(r0 + row) * 128;
    float mx = xr[s0];
    for (int qq = s0 + 1; qq < s1; ++qq) mx = fmaxf(mx, xr[qq]);
    float sum = 0.f;
    for (int qq = s0; qq < s1; ++qq) { float e = __expf(xr[qq] - mx); xr[qq] = e; sum += e; }
    float inv = 1.f / sum;
    for (int qq = s0; qq < s1; ++qq) op[qq] = xr[qq] * inv;
  }
}

// ---- launch ----------------------------------------------------------------
extern "C" void kernel_launch(void* const* d_in, const int* in_sizes, int n_in,
                              void* d_out, int out_size, void* d_ws, size_t ws_size,
                              hipStream_t stream) {
  const float* x0   = (const float*)d_in[0];
  const float* Wi_f = (const float*)d_in[1];
  const float* bi_f = (const float*)d_in[2];
  const float* Wh_f = (const float*)d_in[3];
  const float* bh_f = (const float*)d_in[4];
  const float* Wi_r = (const float*)d_in[5];
  const float* bi_r = (const float*)d_in[6];
  const float* Wh_r = (const float*)d_in[7];
  const float* bh_r = (const float*)d_in[8];
  const float* W1 = (const float*)d_in[9];
  const float* b1 = (const float*)d_in[10];
  const float* W2 = (const float*)d_in[11];
  const float* b2 = (const float*)d_in[12];
  const float* W3 = (const float*)d_in[13];
  const float* b3 = (const float*)d_in[14];
  float* out = (float*)d_out;

  char* ws = (char*)d_ws;
  u16* w1t   = (u16*)(ws + 0);         // 262144 B
  u16* w2t   = (u16*)(ws + 262144);    // 131072 B
  u16* w3t   = (u16*)(ws + 393216);    // 65536 B
  u16* wpack = (u16*)(ws + 458752);    // 1572864 B
  u16* x1    = (u16*)(ws + 2031616);   // 67108864 B

  hipLaunchKernelGGL(prep_all, dim3(12160), dim3(256), 0, stream,
                     Wi_f, Wh_f, Wi_r, Wh_r, W1, W2, W3,
                     wpack, w1t, w2t, w3t, (uint4*)x1);
  hipLaunchKernelGGL(lstm_kernel, dim3(256), dim3(512), 0, stream,
                     x0, wpack, bi_f, bh_f, bi_r, bh_r, x1);
  hipLaunchKernelGGL(mlp_kernel, dim3(1024), dim3(512), 0, stream,
                     x1, w1t, w2t, w3t, b1, b2, b3, out);
}

// Round 17
// 547.113 us; speedup vs baseline: 1.9000x; 1.2374x over previous
//
#include <hip/hip_runtime.h>

typedef unsigned short u16;
typedef unsigned long long u64;
typedef unsigned u32x4_t __attribute__((ext_vector_type(4)));
typedef _Float16 f16x8_t __attribute__((ext_vector_type(8)));
typedef short    i16x8_t __attribute__((ext_vector_type(8)));
typedef float    f32x4_t __attribute__((ext_vector_type(4)));

// force a loaded value to stay materialized in VGPRs (no remat/sinking)
#define PIN(x) asm volatile("" : "+v"(x))

// ---- helpers ---------------------------------------------------------------
static __device__ __forceinline__ u16 f2h(float f) {
  _Float16 h = (_Float16)f;  // RNE
  return __builtin_bit_cast(u16, h);
}
static __device__ __forceinline__ f32x4_t mfma16h(i16x8_t a, i16x8_t b, f32x4_t c) {
  return __builtin_amdgcn_mfma_f32_16x16x32_f16(
      __builtin_bit_cast(f16x8_t, a), __builtin_bit_cast(f16x8_t, b), c, 0, 0, 0);
}
static __device__ __forceinline__ float sigmoidf_(float x) { return 1.f / (1.f + __expf(-x)); }
static __device__ __forceinline__ float tanhf_(float x) { return 1.f - 2.f / (__expf(2.f * x) + 1.f); }

// true iff none of the four u16 lanes equals the sentinel 0x7FFF
static __device__ __forceinline__ bool no_sent(u64 v) {
  u64 x = v ^ 0x7FFF7FFF7FFF7FFFull;  // sentinel lane -> 0x0000
  return (((x - 0x0001000100010001ull) & ~x & 0x8000800080008000ull) == 0);
}
static __device__ __forceinline__ bool ok16(u32x4_t v) {
  u64 a = ((u64)v[1] << 32) | v[0];
  u64 b = ((u64)v[3] << 32) | v[2];
  return no_sent(a) && no_sent(b);
}

// blocking 16B LLC-coherent load (bypasses L1 and L2) -- v13-proven path
static __device__ __forceinline__ u32x4_t llc_load16(const u32x4_t* p) {
  u32x4_t r;
  asm volatile("global_load_dwordx4 %0, %1, off sc0 sc1\n\t"
               "s_waitcnt vmcnt(0)"
               : "=&v"(r) : "v"(p) : "memory");
  return r;
}
// 4B LLC write-through store (lands at the coherence point)
static __device__ __forceinline__ void llc_store4(unsigned* p, unsigned v) {
  asm volatile("global_store_dword %0, %1, off sc0 sc1" :: "v"(p), "v"(v) : "memory");
}

// ---- merged prep: poison x1 + wpack swizzle + MLP W^T, one launch ----------
// blocks [0,8192): poison x1 with f16-NaN sentinel 0x7FFF (h in [-1,1] can
//   never produce it; "!= sentinel" certifies this launch's store landed).
// blocks [8192,11264): wpack[dir][tau][kb][lane][8], tau=jb*4+g; element e:
//   n=g*256+jb*16+mrow, k=kb*32+quad*8+e; val = k<128?Wi[k][n]:Wh[k-128][n].
// blocks [11264,12160): w1t/w2t/w3t = W^T in f16.
__global__ __launch_bounds__(256) void prep_all(
    const float* __restrict__ Wi_f, const float* __restrict__ Wh_f,
    const float* __restrict__ Wi_r, const float* __restrict__ Wh_r,
    const float* __restrict__ W1, const float* __restrict__ W2,
    const float* __restrict__ W3, u16* __restrict__ wpack,
    u16* __restrict__ w1t, u16* __restrict__ w2t, u16* __restrict__ w3t,
    uint4* __restrict__ x1v) {
  int b = blockIdx.x;
  if (b < 8192) {  // poison: 32 B/thread -> 64 MB
    size_t id = (size_t)b * 256 + threadIdx.x;
    const uint4 s = {0x7FFF7FFFu, 0x7FFF7FFFu, 0x7FFF7FFFu, 0x7FFF7FFFu};
    x1v[id * 2] = s;
    x1v[id * 2 + 1] = s;
    return;
  }
  if (b < 11264) {  // wpack
    int id = (b - 8192) * 256 + threadIdx.x;
    if (id >= 786432) return;  // 2*64*12*64*8
    int e = id & 7, r = id >> 3;
    int lane = r & 63; r >>= 6;
    int kb = r % 12; r /= 12;
    int tau = r & 63, dir = r >> 6;
    int mrow = lane & 15, quad = lane >> 4;
    int jb = tau >> 2, g = tau & 3;
    int n = g * 256 + jb * 16 + mrow;
    int k = kb * 32 + quad * 8 + e;
    const float* Wi = dir ? Wi_r : Wi_f;
    const float* Wh = dir ? Wh_r : Wh_f;
    float v = (k < 128) ? Wi[k * 1024 + n] : Wh[(k - 128) * 1024 + n];
    wpack[id] = f2h(v);
    return;
  }
  int id = (b - 11264) * 256 + threadIdx.x;
  if (id < 131072) { int n = id >> 9, k = id & 511; w1t[id] = f2h(W1[k * 256 + n]); return; }
  id -= 131072;
  if (id < 65536) { int n = id >> 8, k = id & 255; w2t[id] = f2h(W2[k * 256 + n]); return; }
  id -= 65536;
  if (id < 32768) { int n = id >> 8, k = id & 255; w3t[id] = f2h(W3[k * 128 + n]); }
}

// ---- bidirectional LSTM = v13 verbatim, normal launch ----------------------
// 256 blocks = q(4 gate-slices) x dir(2) x grp(32 batch-groups of 16 rows).
// Block owns gate-cols tau_g in [16q,16q+16): Wh slice (128 KB) LDS-resident,
// Wi slice in 32 pinned VGPR/wave. Sentinel h-exchange through the LLC
// (poisoned x1, plain sc0|sc1 loads/stores, per-u16 tear check). 256 blocks
// at 156 KB LDS = exactly 1/CU with the GPU otherwise idle -> all blocks
// resident under a normal launch; the poll timeout turns any residency
// violation into a visible wrong answer. Plateau: one LLC store->detect
// round-trip per step (proven irreducible: v12/v13/v15/v16 all ~478).
__global__ __launch_bounds__(512, 2) void lstm_kernel(
    const float* __restrict__ x0, const u16* __restrict__ wpack,
    const float* __restrict__ bi_f, const float* __restrict__ bh_f,
    const float* __restrict__ bi_r, const float* __restrict__ bh_r,
    u16* __restrict__ x1) {
  __shared__ __align__(16) u16 lwh[16][8][64][8];  // 128 KB Wh kb4..11, 16 taus
  __shared__ __align__(16) u16 ah[16][256];        // 8 KB h panel, XOR-swizzled
  __shared__ __align__(16) float gbuf[16][260];    // gate pre-activations (f32)

  const int tid = threadIdx.x;
  const int lane = tid & 63;
  const int w = tid >> 6;             // wave 0..7
  const int bid = blockIdx.x;
  const int q = bid >> 6;             // gate-slice 0..3
  const int rem = bid & 63;
  const int dir = rem >> 5;
  const int grp = rem & 31;
  const int b0 = grp * 16;
  const u16* wpk = wpack + (size_t)dir * (64 * 12 * 64 * 8);
  const float* bi = dir ? bi_r : bi_f;
  const float* bh = dir ? bh_r : bh_f;
  const int mrow = lane & 15, quad = lane >> 4;
  const int tauL0 = 2 * w;            // this wave's 2 local n-tiles

  // biases for the wave's 2 taus
  float bias2[2];
#pragma unroll
  for (int lt = 0; lt < 2; ++lt) {
    int tau_g = 16 * q + tauL0 + lt;
    int n = (tau_g & 3) * 256 + (tau_g >> 2) * 16 + mrow;
    bias2[lt] = bi[n] + bh[n];
  }

  // Wh kb4..11 for the block's 16 taus -> LDS (8192 frags of 16 B)
#pragma unroll
  for (int r = 0; r < 16; ++r) {
    int d = r * 512 + tid;
    int ltau = d >> 9, lkb = (d >> 6) & 7, ll = d & 63;
    *(i16x8_t*)&lwh[ltau][lkb][ll][0] =
        *(const i16x8_t*)(wpk + (((size_t)(16 * q + ltau) * 12 + 4 + lkb) * 64 + ll) * 8);
  }
  // Wi kb0..3 for the wave's 2 taus -> registers (32 VGPR), pinned
  i16x8_t wir[2][4];
#pragma unroll
  for (int lt = 0; lt < 2; ++lt)
#pragma unroll
    for (int kb = 0; kb < 4; ++kb) {
      wir[lt][kb] =
          *(const i16x8_t*)(wpk + (((size_t)(16 * q + tauL0 + lt) * 12 + kb) * 64 + lane) * 8);
      PIN(wir[lt][kb]);
    }
  __syncthreads();  // lwh ready

  // c-state: thread owns 2 adjacent cells (row = tid>>5, jj = 2*(tid&31)+e)
  const int crow = tid >> 5;
  const int cj0 = (tid & 31) * 2;
  float c0 = 0.f, c1 = 0.f;

  // per-lane global base for x-fragment loads (direct, pre-stage)
  const float* xfrag_base = x0 + (size_t)(b0 + mrow) * 16384 + quad * 8;
  // h staging: 16B/thread, coalesced rows; LDS dst is XOR-swizzled
  const int fm = tid >> 5, fj = (tid & 31) * 8;
  const u16* hstage_src = x1 + (size_t)(b0 + fm) * 65536 + dir * 256 + fj;
  u16* ah_dst = &ah[fm][fj ^ ((fm & 7) << 3)];

  for (int t = 0; t < 128; ++t) {
    const int teff = dir ? 127 - t : t;

    // x fragments: direct from x0 (read-only, normal cached loads)
    i16x8_t afx[4];
    {
      const float* xp = xfrag_base + (size_t)teff * 128;
#pragma unroll
      for (int kb = 0; kb < 4; ++kb) {
        float4 va = *(const float4*)(xp + kb * 32);
        float4 vb = *(const float4*)(xp + kb * 32 + 4);
        i16x8_t v;
        v[0] = (short)f2h(va.x); v[1] = (short)f2h(va.y);
        v[2] = (short)f2h(va.z); v[3] = (short)f2h(va.w);
        v[4] = (short)f2h(vb.x); v[5] = (short)f2h(vb.y);
        v[6] = (short)f2h(vb.z); v[7] = (short)f2h(vb.w);
        afx[kb] = v;
      }
    }
    // x-projection MFMAs BEFORE staging (overlap with producers finishing)
    f32x4_t acc[2];
#pragma unroll
    for (int lt = 0; lt < 2; ++lt) {
      float bv = bias2[lt];
      f32x4_t a = {bv, bv, bv, bv};
      a = mfma16h(afx[0], wir[lt][0], a);
      a = mfma16h(afx[1], wir[lt][1], a);
      a = mfma16h(afx[2], wir[lt][2], a);
      a = mfma16h(afx[3], wir[lt][3], a);
      acc[lt] = a;
    }

    // stage h_{t-1}: one 16B LLC-coherent load per thread, retry on sentinel.
    // ah overwrite is safe: all afh reads of step t-1 precede barrier B(t-1),
    // and this stage follows B(t-1) in program order on every thread.
    if (t > 0) {
      const u32x4_t* hsrc = (const u32x4_t*)(hstage_src + (size_t)(t - 1) * 512);
      u32x4_t hv4 = llc_load16(hsrc);
      unsigned iter = 0;
      while (!ok16(hv4)) {
        __builtin_amdgcn_s_sleep(1);
        hv4 = llc_load16(hsrc);
        if (++iter > (1u << 20)) break;  // fail-safe: bug -> wrong, not hang
      }
      *(u32x4_t*)ah_dst = hv4;
    }
    __syncthreads();  // (A) ah ready

    if (t > 0) {  // h-part MFMAs: conflict-free swizzled ds_read_b128
      i16x8_t afh[8];
#pragma unroll
      for (int kb = 0; kb < 8; ++kb)
        afh[kb] = *(const i16x8_t*)&ah[mrow][(kb * 32 + quad * 8) ^ ((mrow & 7) << 3)];
#pragma unroll
      for (int lt = 0; lt < 2; ++lt) {
#pragma unroll
        for (int kb = 0; kb < 8; ++kb)
          acc[lt] = mfma16h(afh[kb], *(const i16x8_t*)&lwh[tauL0 + lt][kb][lane][0], acc[lt]);
      }
    }
    // write gate pre-activations. gbuf overwrite is safe: all gate reads of
    // step t-1 precede barrier A(t) (gate -> stage -> A in program order).
#pragma unroll
    for (int lt = 0; lt < 2; ++lt) {
      int col = (tauL0 + lt) * 16 + mrow;
#pragma unroll
      for (int r = 0; r < 4; ++r) gbuf[quad * 4 + r][col] = acc[lt][r];
    }
    __syncthreads();  // (B) gbuf ready

    // gate phase: 2 cells/thread; col(g) = jb_l*64 + g*16 + mr
    {
      float hv[2];
#pragma unroll
      for (int e = 0; e < 2; ++e) {
        int jj = cj0 + e;
        int base = (jj >> 4) * 64 + (jj & 15);
        float fg = gbuf[crow][base];
        float ig = gbuf[crow][base + 16];
        float ag = gbuf[crow][base + 32];
        float og = gbuf[crow][base + 48];
        float cc = e ? c1 : c0;
        float cv = sigmoidf_(fg) * cc + sigmoidf_(ig) * tanhf_(ag);
        if (e) c1 = cv; else c0 = cv;
        hv[e] = sigmoidf_(og) * tanhf_(cv);
      }
      unsigned pack = (unsigned)f2h(hv[0]) | ((unsigned)f2h(hv[1]) << 16);
      unsigned* hp = (unsigned*)(x1 + ((size_t)((b0 + crow) * 128 + t)) * 512 +
                                 dir * 256 + 64 * q + cj0);
      // plain write-through to LLC; consumers certify arrival via sentinel
      llc_store4(hp, pack);
    }
    // no trailing barrier, no flag: the store IS the signal
  }
}

// ---- fused MLP + heads v19: N-partitioned waves + LDS-staged A -------------
// v18 postmortem: three null occupancy changes -> mlp is L2-TRAFFIC-bound.
// Old layout duplicated B fragments across the 4 row-group waves (1.8 GB of
// L2 reads chip-wide). v19: the 8 waves partition the N dimension (wave owns
// 2 n-tiles stage1/2, 1 n-tile stage3, across ALL 64 rows) so every B
// fragment is loaded exactly once per block; the A tile (x1, 64 KB) is
// staged once into LDS (row stride 520 u16 == 4 dwords mod 32 -> 2-way bank
// access = free). Per-block global traffic 1.875 MB -> 512 KB. Per-(row,col)
// FMA order (kb ascending, same fragments) unchanged -> bit-identical.
__global__ __launch_bounds__(512, 1) void mlp_kernel(
    const u16* __restrict__ x1, const u16* __restrict__ w1t,
    const u16* __restrict__ w2t, const u16* __restrict__ w3t,
    const float* __restrict__ b1, const float* __restrict__ b2,
    const float* __restrict__ b3, float* __restrict__ out) {
  __shared__ __align__(16) u16 xa[64][520];   // 66.6 KB staged x1 tile
  __shared__ __align__(16) u16 X2[64][264];   // 33.8 KB
  __shared__ __align__(16) u16 X3[64][264];   // 33.8 KB
  const int tid = threadIdx.x;
  const int lane = tid & 63;
  const int wv = tid >> 6;                 // wave 0..7 = N-group
  const int mrow = lane & 15, quad = lane >> 4;
  const int r0 = blockIdx.x * 64;
  const f32x4_t zero4 = {0.f, 0.f, 0.f, 0.f};

  // stage x1 tile -> LDS (coalesced 16B chunks)
#pragma unroll
  for (int i = 0; i < 8; ++i) {
    int idx = i * 512 + tid;               // 4096 chunks of 16 B
    int row = idx >> 6, ch = idx & 63;
    *(i16x8_t*)&xa[row][ch * 8] =
        *(const i16x8_t*)(x1 + (size_t)(r0 + row) * 512 + ch * 8);
  }
  __syncthreads();

  // stage 1: X2[64][256] = leaky(xa @ W1 + b1); wave owns n-tiles {2wv,2wv+1}
  {
    f32x4_t acc[2][4];
#pragma unroll
    for (int n = 0; n < 2; ++n)
#pragma unroll
      for (int rg = 0; rg < 4; ++rg) acc[n][rg] = zero4;
    for (int kb = 0; kb < 16; ++kb) {
      int k = kb * 32 + quad * 8;
      i16x8_t bf0 = *(const i16x8_t*)(w1t + ((wv * 2 + 0) * 16 + mrow) * 512 + k);
      i16x8_t bf1 = *(const i16x8_t*)(w1t + ((wv * 2 + 1) * 16 + mrow) * 512 + k);
#pragma unroll
      for (int rg = 0; rg < 4; ++rg) {
        i16x8_t a = *(const i16x8_t*)&xa[rg * 16 + mrow][k];
        acc[0][rg] = mfma16h(a, bf0, acc[0][rg]);
        acc[1][rg] = mfma16h(a, bf1, acc[1][rg]);
      }
    }
#pragma unroll
    for (int n = 0; n < 2; ++n)
#pragma unroll
      for (int rg = 0; rg < 4; ++rg)
#pragma unroll
        for (int r = 0; r < 4; ++r) {
          int m = rg * 16 + quad * 4 + r;
          int col = (wv * 2 + n) * 16 + mrow;
          float v = acc[n][rg][r] + b1[col];
          v = v > 0.f ? v : 0.1f * v;
          X2[m][col] = f2h(v);
        }
  }
  __syncthreads();

  // stage 2: X3[64][256] = leaky(X2 @ W2 + b2), K=256
  {
    f32x4_t acc[2][4];
#pragma unroll
    for (int n = 0; n < 2; ++n)
#pragma unroll
      for (int rg = 0; rg < 4; ++rg) acc[n][rg] = zero4;
#pragma unroll
    for (int kb = 0; kb < 8; ++kb) {
      int k = kb * 32 + quad * 8;
      i16x8_t bf0 = *(const i16x8_t*)(w2t + ((wv * 2 + 0) * 16 + mrow) * 256 + k);
      i16x8_t bf1 = *(const i16x8_t*)(w2t + ((wv * 2 + 1) * 16 + mrow) * 256 + k);
#pragma unroll
      for (int rg = 0; rg < 4; ++rg) {
        i16x8_t a = *(const i16x8_t*)&X2[rg * 16 + mrow][k];
        acc[0][rg] = mfma16h(a, bf0, acc[0][rg]);
        acc[1][rg] = mfma16h(a, bf1, acc[1][rg]);
      }
    }
#pragma unroll
    for (int n = 0; n < 2; ++n)
#pragma unroll
      for (int rg = 0; rg < 4; ++rg)
#pragma unroll
        for (int r = 0; r < 4; ++r) {
          int m = rg * 16 + quad * 4 + r;
          int col = (wv * 2 + n) * 16 + mrow;
          float v = acc[n][rg][r] + b2[col];
          v = v > 0.f ? v : 0.1f * v;
          X3[m][col] = f2h(v);
        }
  }
  __syncthreads();

  // stage 3: XF[64][128] = X3 @ W3 + b3 (fp32; overlays dead X2)
  float (*XF)[130] = (float (*)[130]) & X2[0][0];  // 64*130*4 = 33.3 KB <= X2
  {
    f32x4_t acc[4];
#pragma unroll
    for (int rg = 0; rg < 4; ++rg) acc[rg] = zero4;
#pragma unroll
    for (int kb = 0; kb < 8; ++kb) {
      int k = kb * 32 + quad * 8;
      i16x8_t bf = *(const i16x8_t*)(w3t + (wv * 16 + mrow) * 256 + k);
#pragma unroll
      for (int rg = 0; rg < 4; ++rg) {
        i16x8_t a = *(const i16x8_t*)&X3[rg * 16 + mrow][k];
        acc[rg] = mfma16h(a, bf, acc[rg]);
      }
    }
#pragma unroll
    for (int rg = 0; rg < 4; ++rg)
#pragma unroll
      for (int r = 0; r < 4; ++r) {
        int m = rg * 16 + quad * 4 + r;
        int col = wv * 16 + mrow;
        XF[m][col] = acc[rg][r] + b3[col];
      }
  }
  __syncthreads();

  // heads (parallel, 512 threads): sigmoid 4096 elems -> 8/thread;
  // softmax: 192 (row,seg) tasks -> one per thread (tid<192).
  for (int i = 0; i < 8; ++i) {
    int idx = tid * 8 + i;              // 4096 = 64 rows x 64 cols
    int row = idx >> 6, cc = idx & 63;
    out[(size_t)(r0 + row) * 128 + cc] = sigmoidf_(XF[row][cc]);
  }
  if (tid < 192) {
    int row = tid / 3;
    int s = tid % 3;
    const int s0s[3] = {64, 72, 88};
    const int s1s[3] = {72, 88, 128};
    int s0 = s0s[s], s1 = s1s[s];
    float* xr = XF[row];
    float* op = out + (size_t)(r0 + row) * 128;
    float mx = xr[s0];
    for (int qq = s0 + 1; qq < s1; ++qq) mx = fmaxf(mx, xr[qq]);
    float sum = 0.f;
    for (int qq = s0; qq < s1; ++qq) { float e = __expf(xr[qq] - mx); xr[qq] = e; sum += e; }
    float inv = 1.f / sum;
    for (int qq = s0; qq < s1; ++qq) op[qq] = xr[qq] * inv;
  }
}

// ---- launch ----------------------------------------------------------------
extern "C" void kernel_launch(void* const* d_in, const int* in_sizes, int n_in,
                              void* d_out, int out_size, void* d_ws, size_t ws_size,
                              hipStream_t stream) {
  const float* x0   = (const float*)d_in[0];
  const float* Wi_f = (const float*)d_in[1];
  const float* bi_f = (const float*)d_in[2];
  const float* Wh_f = (const float*)d_in[3];
  const float* bh_f = (const float*)d_in[4];
  const float* Wi_r = (const float*)d_in[5];
  const float* bi_r = (const float*)d_in[6];
  const float* Wh_r = (const float*)d_in[7];
  const float* bh_r = (const float*)d_in[8];
  const float* W1 = (const float*)d_in[9];
  const float* b1 = (const float*)d_in[10];
  const float* W2 = (const float*)d_in[11];
  const float* b2 = (const float*)d_in[12];
  const float* W3 = (const float*)d_in[13];
  const float* b3 = (const float*)d_in[14];
  float* out = (float*)d_out;

  char* ws = (char*)d_ws;
  u16* w1t   = (u16*)(ws + 0);         // 262144 B
  u16* w2t   = (u16*)(ws + 262144);    // 131072 B
  u16* w3t   = (u16*)(ws + 393216);    // 65536 B
  u16* wpack = (u16*)(ws + 458752);    // 1572864 B
  u16* x1    = (u16*)(ws + 2031616);   // 67108864 B

  hipLaunchKernelGGL(prep_all, dim3(12160), dim3(256), 0, stream,
                     Wi_f, Wh_f, Wi_r, Wh_r, W1, W2, W3,
                     wpack, w1t, w2t, w3t, (uint4*)x1);
  hipLaunchKernelGGL(lstm_kernel, dim3(256), dim3(512), 0, stream,
                     x0, wpack, bi_f, bh_f, bi_r, bh_r, x1);
  hipLaunchKernelGGL(mlp_kernel, dim3(1024), dim3(512), 0, stream,
                     x1, w1t, w2t, w3t, b1, b2, b3, out);
}

// Round 18
// 537.872 us; speedup vs baseline: 1.9327x; 1.0172x over previous
//
#include <hip/hip_runtime.h>

typedef unsigned short u16;
typedef unsigned long long u64;
typedef unsigned u32x4_t __attribute__((ext_vector_type(4)));
typedef _Float16 f16x8_t __attribute__((ext_vector_type(8)));
typedef short    i16x8_t __attribute__((ext_vector_type(8)));
typedef float    f32x4_t __attribute__((ext_vector_type(4)));

// force a loaded value to stay materialized in VGPRs (no remat/sinking)
#define PIN(x) asm volatile("" : "+v"(x))

// ---- helpers ---------------------------------------------------------------
static __device__ __forceinline__ u16 f2h(float f) {
  _Float16 h = (_Float16)f;  // RNE
  return __builtin_bit_cast(u16, h);
}
static __device__ __forceinline__ f32x4_t mfma16h(i16x8_t a, i16x8_t b, f32x4_t c) {
  return __builtin_amdgcn_mfma_f32_16x16x32_f16(
      __builtin_bit_cast(f16x8_t, a), __builtin_bit_cast(f16x8_t, b), c, 0, 0, 0);
}
static __device__ __forceinline__ float sigmoidf_(float x) { return 1.f / (1.f + __expf(-x)); }
static __device__ __forceinline__ float tanhf_(float x) { return 1.f - 2.f / (__expf(2.f * x) + 1.f); }

// true iff none of the four u16 lanes equals the sentinel 0x7FFF
static __device__ __forceinline__ bool no_sent(u64 v) {
  u64 x = v ^ 0x7FFF7FFF7FFF7FFFull;  // sentinel lane -> 0x0000
  return (((x - 0x0001000100010001ull) & ~x & 0x8000800080008000ull) == 0);
}
static __device__ __forceinline__ bool ok16(u32x4_t v) {
  u64 a = ((u64)v[1] << 32) | v[0];
  u64 b = ((u64)v[3] << 32) | v[2];
  return no_sent(a) && no_sent(b);
}

// blocking 16B LLC-coherent load (bypasses L1 and L2) -- v13-proven path
static __device__ __forceinline__ u32x4_t llc_load16(const u32x4_t* p) {
  u32x4_t r;
  asm volatile("global_load_dwordx4 %0, %1, off sc0 sc1\n\t"
               "s_waitcnt vmcnt(0)"
               : "=&v"(r) : "v"(p) : "memory");
  return r;
}
// 2B LLC write-through store (lands at the coherence point)
static __device__ __forceinline__ void llc_store2(u16* p, unsigned v) {
  asm volatile("global_store_short %0, %1, off sc0 sc1" :: "v"(p), "v"(v) : "memory");
}

// ---- merged prep: poison x1 + wpack swizzle + MLP W^T, one launch ----------
// blocks [0,8192): poison x1 with f16-NaN sentinel 0x7FFF (h in [-1,1] can
//   never produce it; "!= sentinel" certifies this launch's store landed).
// blocks [8192,11264): wpack[dir][tau][kb][lane][8], tau=jb*4+g; element e:
//   n=g*256+jb*16+mrow, k=kb*32+quad*8+e; val = k<128?Wi[k][n]:Wh[k-128][n].
// blocks [11264,12160): w1t/w2t/w3t = W^T in f16.
__global__ __launch_bounds__(256) void prep_all(
    const float* __restrict__ Wi_f, const float* __restrict__ Wh_f,
    const float* __restrict__ Wi_r, const float* __restrict__ Wh_r,
    const float* __restrict__ W1, const float* __restrict__ W2,
    const float* __restrict__ W3, u16* __restrict__ wpack,
    u16* __restrict__ w1t, u16* __restrict__ w2t, u16* __restrict__ w3t,
    uint4* __restrict__ x1v) {
  int b = blockIdx.x;
  if (b < 8192) {  // poison: 32 B/thread -> 64 MB
    size_t id = (size_t)b * 256 + threadIdx.x;
    const uint4 s = {0x7FFF7FFFu, 0x7FFF7FFFu, 0x7FFF7FFFu, 0x7FFF7FFFu};
    x1v[id * 2] = s;
    x1v[id * 2 + 1] = s;
    return;
  }
  if (b < 11264) {  // wpack
    int id = (b - 8192) * 256 + threadIdx.x;
    if (id >= 786432) return;  // 2*64*12*64*8
    int e = id & 7, r = id >> 3;
    int lane = r & 63; r >>= 6;
    int kb = r % 12; r /= 12;
    int tau = r & 63, dir = r >> 6;
    int mrow = lane & 15, quad = lane >> 4;
    int jb = tau >> 2, g = tau & 3;
    int n = g * 256 + jb * 16 + mrow;
    int k = kb * 32 + quad * 8 + e;
    const float* Wi = dir ? Wi_r : Wi_f;
    const float* Wh = dir ? Wh_r : Wh_f;
    float v = (k < 128) ? Wi[k * 1024 + n] : Wh[(k - 128) * 1024 + n];
    wpack[id] = f2h(v);
    return;
  }
  int id = (b - 11264) * 256 + threadIdx.x;
  if (id < 131072) { int n = id >> 9, k = id & 511; w1t[id] = f2h(W1[k * 256 + n]); return; }
  id -= 131072;
  if (id < 65536) { int n = id >> 8, k = id & 255; w2t[id] = f2h(W2[k * 256 + n]); return; }
  id -= 65536;
  if (id < 32768) { int n = id >> 8, k = id & 255; w3t[id] = f2h(W3[k * 128 + n]); }
}

// ---- bidirectional LSTM v20: all-4-gates-per-wave, in-register gate phase --
// 256 blocks = q(4 gate-slices) x dir(2) x grp(32 batch-groups of 16 rows),
// but now 256 threads = 4 waves; wave w owns jb = 4q+w -> taus 16q+4w+{0..3}
// (ALL FOUR GATES of one 16x16 cell tile). MFMA C-layout puts f/i/a/o for
// cell (quad*4+r, mrow) in the same lane at the same r across the 4 accs ->
// gate nonlinearity + c-state run fully in registers; the gbuf LDS round-trip
// and barrier B of v13 are DELETED, so h publishes ~0.5-1us earlier in the
// inter-block serial loop. ah is double-buffered (stage(t) writes ah[t&1];
// readers of it last touched it at t-2, separated by barrier(t-1) -> one
// barrier/step is sufficient). Exchange protocol (sentinel 0x7FFF, sc0|sc1
// LLC loads/stores) is v13-verbatim; accumulation order per (cell,tau)
// unchanged (bias -> Wi kb0..3 -> Wh kb0..7) -> bit-identical numerics.
// launch_bounds(256,1) -> 512-VGPR RA budget (need ~156; v6/v7's cap was at
// higher occupancy declarations).
__global__ __launch_bounds__(256, 1) void lstm_kernel(
    const float* __restrict__ x0, const u16* __restrict__ wpack,
    const float* __restrict__ bi_f, const float* __restrict__ bh_f,
    const float* __restrict__ bi_r, const float* __restrict__ bh_r,
    u16* __restrict__ x1) {
  __shared__ __align__(16) u16 lwh[16][8][64][8];  // 128 KB Wh kb4..11, 16 taus
  __shared__ __align__(16) u16 ah[2][16][256];     // 16 KB h panel, dbuf + swz

  const int tid = threadIdx.x;
  const int lane = tid & 63;
  const int w = tid >> 6;             // wave 0..3 (owns jb = 4q+w)
  const int bid = blockIdx.x;
  const int q = bid >> 6;             // gate-slice 0..3
  const int rem = bid & 63;
  const int dir = rem >> 5;
  const int grp = rem & 31;
  const int b0 = grp * 16;
  const u16* wpk = wpack + (size_t)dir * (64 * 12 * 64 * 8);
  const float* bi = dir ? bi_r : bi_f;
  const float* bh = dir ? bh_r : bh_f;
  const int mrow = lane & 15, quad = lane >> 4;
  const int tauL0 = 4 * w;            // wave's first local tau (of 16)

  // biases for the wave's 4 gates (same jb = 4q+w)
  float bias4[4];
#pragma unroll
  for (int g = 0; g < 4; ++g) {
    int n = g * 256 + (4 * q + w) * 16 + mrow;
    bias4[g] = bi[n] + bh[n];
  }

  // Wh kb4..11 for the block's 16 taus -> LDS (8192 frags of 16 B, 32/thread)
#pragma unroll
  for (int r = 0; r < 32; ++r) {
    int d = r * 256 + tid;
    int ltau = d >> 9, lkb = (d >> 6) & 7, ll = d & 63;
    *(i16x8_t*)&lwh[ltau][lkb][ll][0] =
        *(const i16x8_t*)(wpk + (((size_t)(16 * q + ltau) * 12 + 4 + lkb) * 64 + ll) * 8);
  }
  // Wi kb0..3 for the wave's 4 taus -> registers (64 VGPR), pinned
  i16x8_t wir[4][4];
#pragma unroll
  for (int g = 0; g < 4; ++g)
#pragma unroll
    for (int kb = 0; kb < 4; ++kb) {
      wir[g][kb] =
          *(const i16x8_t*)(wpk + (((size_t)(16 * q + tauL0 + g) * 12 + kb) * 64 + lane) * 8);
      PIN(wir[g][kb]);
    }
  // h_{-1} = 0 (both parities)
  for (int i = tid; i < 2 * 16 * 256; i += 256) ((u16*)ah)[i] = 0;
  __syncthreads();  // lwh + ah ready

  // c-state: lane owns 4 cells (row = quad*4+r, col = 64q + w*16 + mrow)
  float c4[4] = {};

  // per-lane global base for x-fragment loads (direct, pre-stage)
  const float* xfrag_base = x0 + (size_t)(b0 + mrow) * 16384 + quad * 8;
  // h staging: 32B/thread (2x16B polls), coalesced rows; LDS dst XOR-swizzled
  const int fm = tid >> 4, fj = (tid & 15) * 16;
  const int swz = (fm & 7) << 3;
  const u16* hstage_src = x1 + (size_t)(b0 + fm) * 65536 + dir * 256 + fj;
  // per-lane h-store base: row quad*4, col 64q + w*16 + mrow at time t
  u16* hstore_base = x1 + (size_t)(b0 + quad * 4) * 65536 + dir * 256 + 64 * q + w * 16 + mrow;

  for (int t = 0; t < 128; ++t) {
    const int teff = dir ? 127 - t : t;
    const int par = t & 1;

    // x fragments: direct from x0 (read-only, normal cached loads)
    i16x8_t afx[4];
    {
      const float* xp = xfrag_base + (size_t)teff * 128;
#pragma unroll
      for (int kb = 0; kb < 4; ++kb) {
        float4 va = *(const float4*)(xp + kb * 32);
        float4 vb = *(const float4*)(xp + kb * 32 + 4);
        i16x8_t v;
        v[0] = (short)f2h(va.x); v[1] = (short)f2h(va.y);
        v[2] = (short)f2h(va.z); v[3] = (short)f2h(va.w);
        v[4] = (short)f2h(vb.x); v[5] = (short)f2h(vb.y);
        v[6] = (short)f2h(vb.z); v[7] = (short)f2h(vb.w);
        afx[kb] = v;
      }
    }
    // x-projection MFMAs BEFORE staging (overlap with producers finishing)
    f32x4_t acc[4];
#pragma unroll
    for (int g = 0; g < 4; ++g) {
      float bv = bias4[g];
      f32x4_t a = {bv, bv, bv, bv};
      a = mfma16h(afx[0], wir[g][0], a);
      a = mfma16h(afx[1], wir[g][1], a);
      a = mfma16h(afx[2], wir[g][2], a);
      a = mfma16h(afx[3], wir[g][3], a);
      acc[g] = a;
    }

    // stage h_{t-1} into ah[par]: two 16B LLC polls/thread, retry on sentinel.
    // ah[par] overwrite is safe: its readers ran at t-2, and barrier(t-1)
    // separates them from this write on every thread.
    if (t > 0) {
      const u32x4_t* hsrc = (const u32x4_t*)(hstage_src + (size_t)(t - 1) * 512);
      u32x4_t h0 = llc_load16(hsrc);
      u32x4_t h1 = llc_load16(hsrc + 1);
      unsigned iter = 0;
      while (!(ok16(h0) && ok16(h1))) {
        __builtin_amdgcn_s_sleep(1);
        if (!ok16(h0)) h0 = llc_load16(hsrc);
        if (!ok16(h1)) h1 = llc_load16(hsrc + 1);
        if (++iter > (1u << 20)) break;  // fail-safe: bug -> wrong, not hang
      }
      u16* abase = &ah[par][0][0];
      *(u32x4_t*)(abase + fm * 256 + (fj ^ swz)) = h0;
      *(u32x4_t*)(abase + fm * 256 + ((fj + 8) ^ swz)) = h1;
    }
    __syncthreads();  // (A) ah[par] ready -- the ONLY barrier per step

    if (t > 0) {  // h-part MFMAs: conflict-free swizzled ds_read_b128
      i16x8_t afh[8];
#pragma unroll
      for (int kb = 0; kb < 8; ++kb)
        afh[kb] = *(const i16x8_t*)&ah[par][mrow][(kb * 32 + quad * 8) ^ ((mrow & 7) << 3)];
#pragma unroll
      for (int g = 0; g < 4; ++g) {
#pragma unroll
        for (int kb = 0; kb < 8; ++kb)
          acc[g] = mfma16h(afh[kb], *(const i16x8_t*)&lwh[tauL0 + g][kb][lane][0], acc[g]);
      }
    }

    // gate phase: fully in-register (f/i/a/o of cell (quad*4+r, mrow) are
    // acc[0..3][r] in this lane); store h immediately (2B sc0|sc1 stores,
    // 16-lane-contiguous 32B segments per quad-row).
#pragma unroll
    for (int r = 0; r < 4; ++r) {
      float fv = sigmoidf_(acc[0][r]);
      float iv = sigmoidf_(acc[1][r]);
      float av = tanhf_(acc[2][r]);
      float ov = sigmoidf_(acc[3][r]);
      float cv = fv * c4[r] + iv * av;
      c4[r] = cv;
      float hv = ov * tanhf_(cv);
      llc_store2(hstore_base + ((size_t)r * 128 + t) * 512, (unsigned)f2h(hv));
    }
    // no trailing barrier, no flag: the store IS the signal
  }
}

// ---- fused MLP + heads v19: N-partitioned waves + LDS-staged A (unchanged) -
// 8 waves partition N (wave owns 2 n-tiles stage1/2, 1 n-tile stage3, across
// all 64 rows) -> every B fragment loaded once per block; A tile staged once
// into LDS. Per-block global traffic 512 KB. Bit-identical math.
__global__ __launch_bounds__(512, 1) void mlp_kernel(
    const u16* __restrict__ x1, const u16* __restrict__ w1t,
    const u16* __restrict__ w2t, const u16* __restrict__ w3t,
    const float* __restrict__ b1, const float* __restrict__ b2,
    const float* __restrict__ b3, float* __restrict__ out) {
  __shared__ __align__(16) u16 xa[64][520];   // 66.6 KB staged x1 tile
  __shared__ __align__(16) u16 X2[64][264];   // 33.8 KB
  __shared__ __align__(16) u16 X3[64][264];   // 33.8 KB
  const int tid = threadIdx.x;
  const int lane = tid & 63;
  const int wv = tid >> 6;                 // wave 0..7 = N-group
  const int mrow = lane & 15, quad = lane >> 4;
  const int r0 = blockIdx.x * 64;
  const f32x4_t zero4 = {0.f, 0.f, 0.f, 0.f};

  // stage x1 tile -> LDS (coalesced 16B chunks)
#pragma unroll
  for (int i = 0; i < 8; ++i) {
    int idx = i * 512 + tid;               // 4096 chunks of 16 B
    int row = idx >> 6, ch = idx & 63;
    *(i16x8_t*)&xa[row][ch * 8] =
        *(const i16x8_t*)(x1 + (size_t)(r0 + row) * 512 + ch * 8);
  }
  __syncthreads();

  // stage 1: X2[64][256] = leaky(xa @ W1 + b1); wave owns n-tiles {2wv,2wv+1}
  {
    f32x4_t acc[2][4];
#pragma unroll
    for (int n = 0; n < 2; ++n)
#pragma unroll
      for (int rg = 0; rg < 4; ++rg) acc[n][rg] = zero4;
    for (int kb = 0; kb < 16; ++kb) {
      int k = kb * 32 + quad * 8;
      i16x8_t bf0 = *(const i16x8_t*)(w1t + ((wv * 2 + 0) * 16 + mrow) * 512 + k);
      i16x8_t bf1 = *(const i16x8_t*)(w1t + ((wv * 2 + 1) * 16 + mrow) * 512 + k);
#pragma unroll
      for (int rg = 0; rg < 4; ++rg) {
        i16x8_t a = *(const i16x8_t*)&xa[rg * 16 + mrow][k];
        acc[0][rg] = mfma16h(a, bf0, acc[0][rg]);
        acc[1][rg] = mfma16h(a, bf1, acc[1][rg]);
      }
    }
#pragma unroll
    for (int n = 0; n < 2; ++n)
#pragma unroll
      for (int rg = 0; rg < 4; ++rg)
#pragma unroll
        for (int r = 0; r < 4; ++r) {
          int m = rg * 16 + quad * 4 + r;
          int col = (wv * 2 + n) * 16 + mrow;
          float v = acc[n][rg][r] + b1[col];
          v = v > 0.f ? v : 0.1f * v;
          X2[m][col] = f2h(v);
        }
  }
  __syncthreads();

  // stage 2: X3[64][256] = leaky(X2 @ W2 + b2), K=256
  {
    f32x4_t acc[2][4];
#pragma unroll
    for (int n = 0; n < 2; ++n)
#pragma unroll
      for (int rg = 0; rg < 4; ++rg) acc[n][rg] = zero4;
#pragma unroll
    for (int kb = 0; kb < 8; ++kb) {
      int k = kb * 32 + quad * 8;
      i16x8_t bf0 = *(const i16x8_t*)(w2t + ((wv * 2 + 0) * 16 + mrow) * 256 + k);
      i16x8_t bf1 = *(const i16x8_t*)(w2t + ((wv * 2 + 1) * 16 + mrow) * 256 + k);
#pragma unroll
      for (int rg = 0; rg < 4; ++rg) {
        i16x8_t a = *(const i16x8_t*)&X2[rg * 16 + mrow][k];
        acc[0][rg] = mfma16h(a, bf0, acc[0][rg]);
        acc[1][rg] = mfma16h(a, bf1, acc[1][rg]);
      }
    }
#pragma unroll
    for (int n = 0; n < 2; ++n)
#pragma unroll
      for (int rg = 0; rg < 4; ++rg)
#pragma unroll
        for (int r = 0; r < 4; ++r) {
          int m = rg * 16 + quad * 4 + r;
          int col = (wv * 2 + n) * 16 + mrow;
          float v = acc[n][rg][r] + b2[col];
          v = v > 0.f ? v : 0.1f * v;
          X3[m][col] = f2h(v);
        }
  }
  __syncthreads();

  // stage 3: XF[64][128] = X3 @ W3 + b3 (fp32; overlays dead X2)
  float (*XF)[130] = (float (*)[130]) & X2[0][0];  // 64*130*4 = 33.3 KB <= X2
  {
    f32x4_t acc[4];
#pragma unroll
    for (int rg = 0; rg < 4; ++rg) acc[rg] = zero4;
#pragma unroll
    for (int kb = 0; kb < 8; ++kb) {
      int k = kb * 32 + quad * 8;
      i16x8_t bf = *(const i16x8_t*)(w3t + (wv * 16 + mrow) * 256 + k);
#pragma unroll
      for (int rg = 0; rg < 4; ++rg) {
        i16x8_t a = *(const i16x8_t*)&X3[rg * 16 + mrow][k];
        acc[rg] = mfma16h(a, bf, acc[rg]);
      }
    }
#pragma unroll
    for (int rg = 0; rg < 4; ++rg)
#pragma unroll
      for (int r = 0; r < 4; ++r) {
        int m = rg * 16 + quad * 4 + r;
        int col = wv * 16 + mrow;
        XF[m][col] = acc[rg][r] + b3[col];
      }
  }
  __syncthreads();

  // heads (parallel, 512 threads): sigmoid 4096 elems -> 8/thread;
  // softmax: 192 (row,seg) tasks -> one per thread (tid<192).
  for (int i = 0; i < 8; ++i) {
    int idx = tid * 8 + i;              // 4096 = 64 rows x 64 cols
    int row = idx >> 6, cc = idx & 63;
    out[(size_t)(r0 + row) * 128 + cc] = sigmoidf_(XF[row][cc]);
  }
  if (tid < 192) {
    int row = tid / 3;
    int s = tid % 3;
    const int s0s[3] = {64, 72, 88};
    const int s1s[3] = {72, 88, 128};
    int s0 = s0s[s], s1 = s1s[s];
    float* xr = XF[row];
    float* op = out + (size_t)(r0 + row) * 128;
    float mx = xr[s0];
    for (int qq = s0 + 1; qq < s1; ++qq) mx = fmaxf(mx, xr[qq]);
    float sum = 0.f;
    for (int qq = s0; qq < s1; ++qq) { float e = __expf(xr[qq] - mx); xr[qq] = e; sum += e; }
    float inv = 1.f / sum;
    for (int qq = s0; qq < s1; ++qq) op[qq] = xr[qq] * inv;
  }
}

// ---- launch ----------------------------------------------------------------
extern "C" void kernel_launch(void* const* d_in, const int* in_sizes, int n_in,
                              void* d_out, int out_size, void* d_ws, size_t ws_size,
                              hipStream_t stream) {
  const float* x0   = (const float*)d_in[0];
  const float* Wi_f = (const float*)d_in[1];
  const float* bi_f = (const float*)d_in[2];
  const float* Wh_f = (const float*)d_in[3];
  const float* bh_f = (const float*)d_in[4];
  const float* Wi_r = (const float*)d_in[5];
  const float* bi_r = (const float*)d_in[6];
  const float* Wh_r = (const float*)d_in[7];
  const float* bh_r = (const float*)d_in[8];
  const float* W1 = (const float*)d_in[9];
  const float* b1 = (const float*)d_in[10];
  const float* W2 = (const float*)d_in[11];
  const float* b2 = (const float*)d_in[12];
  const float* W3 = (const float*)d_in[13];
  const float* b3 = (const float*)d_in[14];
  float* out = (float*)d_out;

  char* ws = (char*)d_ws;
  u16* w1t   = (u16*)(ws + 0);         // 262144 B
  u16* w2t   = (u16*)(ws + 262144);    // 131072 B
  u16* w3t   = (u16*)(ws + 393216);    // 65536 B
  u16* wpack = (u16*)(ws + 458752);    // 1572864 B
  u16* x1    = (u16*)(ws + 2031616);   // 67108864 B

  hipLaunchKernelGGL(prep_all, dim3(12160), dim3(256), 0, stream,
                     Wi_f, Wh_f, Wi_r, Wh_r, W1, W2, W3,
                     wpack, w1t, w2t, w3t, (uint4*)x1);
  hipLaunchKernelGGL(lstm_kernel, dim3(256), dim3(256), 0, stream,
                     x0, wpack, bi_f, bh_f, bi_r, bh_r, x1);
  hipLaunchKernelGGL(mlp_kernel, dim3(1024), dim3(512), 0, stream,
                     x1, w1t, w2t, w3t, b1, b2, b3, out);
}